// Round 6
// baseline (1524.907 us; speedup 1.0000x reference)
//
#include <hip/hip_runtime.h>
#include <math.h>

// Problem dims: B=256, T=64, N=128, M=256, P=256, YD=1
// 256 blocks x 512 threads (8 waves). Group = 16 blocks = 16 batches; block role mt = m-tile.

// Workspace layout (float offsets)
#define OFF_XWT   0u          // [256][64][128]  XWt[b][j][n]   (block-local)
#define OFF_XEWT  2097152u    // [256][256][64]  XeWt[b][j][t'] (block-local)
#define OFF_XE    6291456u    // [256][64][256]  Xe[b][t][m]    (sc1 w, sc1 r once)
#define OFF_HE    10485760u   // [2][16][256][16] h_e transposed: [buf][grp][k][bl]
#define OFF_HD    10616832u   // [2][16][256][16] h_d transposed
#define OFF_SB    10747904u   // [2][256][64]    S accum        (atomic add / sc1 r+zero)
#define OFF_SDB   10780672u   // [2][256][256]   Sd accum       (atomic add / sc1 r+zero)
#define OFF_XA    10911744u   // [16][128][16]   x*alpha transposed: [grp][n][bl]
#define OFF_CTX   10944512u   // [256][256]      ctx            (sc1 w/r)
#define OFF_YT    11010048u   // [256]           y_tilde        (sc1 w/r)
#define OFF_BAR   11010304u   // 16 groups x 32 u32
#define WS_END    11010816u

// LDS (floats): SLAB (weights, persistent) | PER (small persistent) | SCR (per-phase)
#define SLAB_F 24576
#define PER_F  2432
#define SCR_F  12288
#define SMEM_F (SLAB_F + PER_F + SCR_F)
#define SMEM_BYTES (SMEM_F * 4)   // 157184 B <= 160 KB

__device__ __forceinline__ float fast_tanh(float x) {
  float xc = fminf(15.f, fmaxf(-15.f, x));
  float e = __expf(2.f * xc);
  return 1.f - 2.f * __builtin_amdgcn_rcpf(e + 1.f);
}
__device__ __forceinline__ float fast_sig(float x) {
  float xc = fminf(30.f, fmaxf(-30.f, x));
  return __builtin_amdgcn_rcpf(1.f + __expf(-xc));
}
__device__ __forceinline__ float wave_max(float v) {
#pragma unroll
  for (int o = 32; o; o >>= 1) v = fmaxf(v, __shfl_xor(v, o));
  return v;
}
__device__ __forceinline__ float wave_sum(float v) {
#pragma unroll
  for (int o = 32; o; o >>= 1) v += __shfl_xor(v, o);
  return v;
}
__device__ __forceinline__ float dot4(float4 a, float4 b) {
  return a.x*b.x + a.y*b.y + a.z*b.z + a.w*b.w;
}

// ---- device-scope (sc1) coherent helpers ----
// float4 only as ASM OUTPUT ("=&v"); struct inputs in "v" don't compile.
__device__ __forceinline__ void st1_sc1(float* p, float v) {
  asm volatile("global_store_dword %0, %1, off sc1" :: "v"(p), "v"(v) : "memory");
}
__device__ __forceinline__ void ld1q_sc1(float4& a, const float* pa) {
  asm volatile("global_load_dwordx4 %0, %1, off sc1\n\ts_waitcnt vmcnt(0)"
               : "=&v"(a) : "v"(pa) : "memory");
}
// non-waiting variants: pair with vm0()
__device__ __forceinline__ void ld1q_nw(float4& a, const float* pa) {
  asm volatile("global_load_dwordx4 %0, %1, off sc1"
               : "=&v"(a) : "v"(pa) : "memory");
}
__device__ __forceinline__ void ld1s_nw(float& a, const float* pa) {
  asm volatile("global_load_dword %0, %1, off sc1"
               : "=&v"(a) : "v"(pa) : "memory");
}
__device__ __forceinline__ void vm0() {
  asm volatile("s_waitcnt vmcnt(0)" ::: "memory");
}
__device__ __forceinline__ float ld1s_sc1(const float* p) {
  float v;
  asm volatile("global_load_dword %0, %1, off sc1\n\ts_waitcnt vmcnt(0)"
               : "=&v"(v) : "v"(p) : "memory");
  return v;
}
__device__ __forceinline__ void ld8s_sc1(
    float& a0,float& a1,float& a2,float& a3,float& a4,float& a5,float& a6,float& a7,
    const float* p0,const float* p1,const float* p2,const float* p3,
    const float* p4,const float* p5,const float* p6,const float* p7) {
  asm volatile(
      "global_load_dword %0, %8, off sc1\n\t"
      "global_load_dword %1, %9, off sc1\n\t"
      "global_load_dword %2, %10, off sc1\n\t"
      "global_load_dword %3, %11, off sc1\n\t"
      "global_load_dword %4, %12, off sc1\n\t"
      "global_load_dword %5, %13, off sc1\n\t"
      "global_load_dword %6, %14, off sc1\n\t"
      "global_load_dword %7, %15, off sc1\n\t"
      "s_waitcnt vmcnt(0)"
      : "=&v"(a0),"=&v"(a1),"=&v"(a2),"=&v"(a3),
        "=&v"(a4),"=&v"(a5),"=&v"(a6),"=&v"(a7)
      : "v"(p0),"v"(p1),"v"(p2),"v"(p3),"v"(p4),"v"(p5),"v"(p6),"v"(p7)
      : "memory");
}
__device__ __forceinline__ void atomic_add_sc1(float* p, float v) {
  asm volatile("global_atomic_add_f32 %0, %1, off sc1" :: "v"(p), "v"(v) : "memory");
}

// a_i (batch b4*4+i, gates.xyzw) += xv_i * wv
#define FMA16V(a0,a1,a2,a3,xv,wv) \
  a0.x += xv.x*wv.x; a0.y += xv.x*wv.y; a0.z += xv.x*wv.z; a0.w += xv.x*wv.w; \
  a1.x += xv.y*wv.x; a1.y += xv.y*wv.y; a1.z += xv.y*wv.z; a1.w += xv.y*wv.w; \
  a2.x += xv.z*wv.x; a2.y += xv.z*wv.y; a2.z += xv.z*wv.z; a2.w += xv.z*wv.w; \
  a3.x += xv.w*wv.x; a3.y += xv.w*wv.y; a3.z += xv.w*wv.z; a3.w += xv.w*wv.w;

// Fence-free 16-block group barrier (monotonic counter, relaxed agent atomics).
__device__ __forceinline__ void group_barrier(unsigned* bar, unsigned& n) {
  n += 16;
  asm volatile("s_waitcnt vmcnt(0)" ::: "memory");
  __syncthreads();
  if (threadIdx.x == 0) {
    __hip_atomic_fetch_add(bar, 1u, __ATOMIC_RELAXED, __HIP_MEMORY_SCOPE_AGENT);
    unsigned cur;
    do {
      cur = __hip_atomic_load(bar, __ATOMIC_RELAXED, __HIP_MEMORY_SCOPE_AGENT);
    } while (cur < n);
  }
  __syncthreads();
}

__global__ void darnn_init(float* __restrict__ ws, float* __restrict__ out) {
  unsigned i = blockIdx.x * 256u + threadIdx.x;
  const unsigned span = WS_END - OFF_HE;
  for (unsigned idx = i; idx < span; idx += gridDim.x * 256u) ws[OFF_HE + idx] = 0.f;
  if (i < 256u) out[i] = 0.f;
}

__global__ __launch_bounds__(512, 2) void darnn_main(
    const float* __restrict__ in,   const float* __restrict__ WUe,   const float* __restrict__ ve,
    const float* __restrict__ Wih_e,const float* __restrict__ Whh_e,
    const float* __restrict__ bih_e,const float* __restrict__ bhh_e,
    const float* __restrict__ WUd,  const float* __restrict__ vd,
    const float* __restrict__ wbt,  const float* __restrict__ Wih_d,
    const float* __restrict__ Whh_d,const float* __restrict__ bih_d, const float* __restrict__ bhh_d,
    const float* __restrict__ WbW,  const float* __restrict__ Wbb,
    const float* __restrict__ vbW,  const float* __restrict__ vbb,
    float* __restrict__ ws, float* __restrict__ out)
{
  extern __shared__ __align__(16) float sm[];
  float* SLAB = sm;
  float* PER  = sm + SLAB_F;
  float* SCR  = sm + SLAB_F + PER_F;
  const int tid = threadIdx.x;
  const int bid = blockIdx.x;
  const int grp = bid >> 4;
  const int mt  = bid & 15;
  const int b0  = grp << 4;

  float* XWt  = ws + OFF_XWT;
  float* XeWt = ws + OFF_XEWT;
  float* Xe   = ws + OFF_XE;
  unsigned* barp = (unsigned*)(ws + OFF_BAR) + grp * 32;
  unsigned barn = 0;

  // PER (encoder): wue_s [64][36]; ve_s [64] @2304; bsum_e [64] @2368
  float* wue_s  = PER;
  float* ve_s   = PER + 2304;
  float* bsum_e = PER + 2368;

  // ---- one-time encoder staging ----
  {
    // encoder weight slab: SLAB[k*64 + r], r = ml*4 + gate, k < 384
    int r = tid & 63, kq = tid >> 6;
    int grow = (r & 3) * 256 + mt * 16 + (r >> 2);
#pragma unroll 4
    for (int q = 0; q < 12; ++q) {
      int k = kq * 48 + q * 4;
      float4 wv = (k < 128) ? *(const float4*)(Wih_e + grow * 128 + k)
                            : *(const float4*)(Whh_e + grow * 256 + (k - 128));
      SLAB[(k + 0) * 64 + r] = wv.x; SLAB[(k + 1) * 64 + r] = wv.y;
      SLAB[(k + 2) * 64 + r] = wv.z; SLAB[(k + 3) * 64 + r] = wv.w;
    }
    // wue_s
    {
      int lin = tid * 4;
      int j = lin >> 5, c0 = lin & 31;
      int col = (c0 < 16) ? (mt * 16 + c0) : (256 + mt * 16 + (c0 - 16));
      float4 wv = *(const float4*)(WUe + j * 576 + col);
      *(float4*)(wue_s + j * 36 + c0) = wv;
    }
    if (tid < 64) {
      ve_s[tid] = ve[tid];
      int g = tid >> 4, m2 = tid & 15, m = mt * 16 + m2;
      bsum_e[tid] = bih_e[g * 256 + m] + bhh_e[g * 256 + m];
    }
  }

  // ---------------- P1: XWt[bid][j][n] = sum_k X[bid][k][n] * WU_e[j][512+k]
  {
    float* Xs = SCR;  // [128][68]
    const float* Xb = in + bid * 8256;
    __syncthreads();
    for (int it = 0; it < 16; ++it) {
      int lin = tid + it * 512;
      int k = lin >> 7, n = lin & 127;
      Xs[n * 68 + k] = Xb[k * 129 + n];
    }
    __syncthreads();
    int j = tid & 63, nh = tid >> 6;
    float acc[16];
#pragma unroll
    for (int i = 0; i < 16; ++i) acc[i] = 0.f;
    const float* wrow = WUe + j * 576 + 512;
    for (int kc = 0; kc < 4; ++kc) {
      float4 w0 = *(const float4*)(wrow + kc * 16 + 0);
      float4 w1 = *(const float4*)(wrow + kc * 16 + 4);
      float4 w2 = *(const float4*)(wrow + kc * 16 + 8);
      float4 w3 = *(const float4*)(wrow + kc * 16 + 12);
#pragma unroll
      for (int ni = 0; ni < 16; ++ni) {
        const float* xp = Xs + (nh * 16 + ni) * 68 + kc * 16;
        acc[ni] += dot4(*(const float4*)(xp + 0),  w0) + dot4(*(const float4*)(xp + 4),  w1)
                 + dot4(*(const float4*)(xp + 8),  w2) + dot4(*(const float4*)(xp + 12), w3);
      }
    }
    float* dst = XWt + bid * 8192 + j * 128 + nh * 16;
#pragma unroll
    for (int ni = 0; ni < 16; ++ni) dst[ni] = acc[ni];
    __syncthreads();
  }

  // hoist attention-weight row into regs (constant over t)
  float4 whc[8];
#pragma unroll
  for (int q = 0; q < 8; ++q) whc[q] = *(const float4*)(wue_s + (tid & 63) * 36 + q * 4);
  float4 bsE = {0,0,0,0};
  {
    int m2 = tid & 15;
    bsE.x = bsum_e[m2]; bsE.y = bsum_e[16 + m2];
    bsE.z = bsum_e[32 + m2]; bsE.w = bsum_e[48 + m2];
  }
  float c_reg = 0.f;   // c-state for thread (m2 = tid&15, bl = (tid>>4)&15), tid<256

  // ================ ENCODER: 64 steps ================
  for (int t = 0; t < 64; ++t) {
    const int rd = t & 1, wr2 = (t + 1) & 1;
    // ---- EA: input attention for b = bid (+ prefetch h into xah rows 128..383)
    {
      float* Sj  = SCR;          // [64]
      float* Eh  = SCR + 64;     // [4][128]
      float* r8  = SCR + 576;    // [8]
      float* xah = SCR + 1024;   // [384][20] (h rows prefetched now; XA rows in EB)
      {
        int kh = tid >> 2, i4 = (tid & 3) * 4;
        const float* hb = ws + OFF_HE + (unsigned)rd * 65536 + (unsigned)grp * 4096;
        float4 h0, h1, sv;
        ld1q_nw(h0, hb + kh * 16 + i4);
        ld1q_nw(h1, hb + (128 + kh) * 16 + i4);
        float* sp = ws + OFF_SB + (unsigned)rd * 16384 + (unsigned)bid * 64 + tid * 4;
        if (tid < 16) ld1q_nw(sv, sp);
        vm0();
        *(float4*)(xah + (128 + kh) * 20 + i4) = h0;
        *(float4*)(xah + (256 + kh) * 20 + i4) = h1;
        if (tid < 16) {
          st1_sc1(sp + 0, 0.f); st1_sc1(sp + 1, 0.f);
          st1_sc1(sp + 2, 0.f); st1_sc1(sp + 3, 0.f);
          *(float4*)(Sj + tid * 4) = sv;
        }
      }
      __syncthreads();
      {
        int n = tid & 127, jh = tid >> 7;
        const float* xwp = XWt + bid * 8192 + n;
        float e = 0.f;
#pragma unroll
        for (int jj = 0; jj < 16; ++jj) {
          int j = jh * 16 + jj;
          e += ve_s[j] * fast_tanh(xwp[j << 7] + Sj[j]);
        }
        Eh[jh * 128 + n] = e;
      }
      __syncthreads();
      int lane = tid & 63, wid = tid >> 6;
      float En = (tid < 128) ? (Eh[tid] + Eh[128 + tid] + Eh[256 + tid] + Eh[384 + tid]) : -1e30f;
      float mx = wave_max(En);
      if (tid < 128 && lane == 0) r8[wid] = mx;
      __syncthreads();
      mx = fmaxf(r8[0], r8[1]);
      float ex = (tid < 128) ? __expf(En - mx) : 0.f;
      float sw = wave_sum(ex);
      if (tid < 128 && lane == 0) r8[4 + wid] = sw;
      __syncthreads();
      float tot = r8[4] + r8[5];
      if (tid < 128)
        st1_sc1(ws + OFF_XA + (unsigned)grp * 2048 + tid * 16 + mt,
                in[bid * 8256 + t * 129 + tid] * (ex / tot));
    }
    group_barrier(barp, barn);

    // ---- EB: gates GEMM (K=384, x via b128 broadcast) + pointwise + S atomics
    {
      float* xah = SCR + 1024;     // [384][20]
      float* red = SCR;            // [512][20] alias (written after k-loop)
      float* hcs = SCR + 10240;    // [16][32]
      {
        int k = tid >> 2, i4 = (tid & 3) * 4;
        float4 q;
        ld1q_sc1(q, ws + OFF_XA + (unsigned)grp * 2048 + k * 16 + i4);
        *(float4*)(xah + k * 20 + i4) = q;
      }
      __syncthreads();
      const int ks = tid >> 6, ml = (tid >> 2) & 15, b4 = tid & 3;
      float4 a0 = {0,0,0,0}, a1 = {0,0,0,0}, a2 = {0,0,0,0}, a3 = {0,0,0,0};
      {
        const float* xp = xah + (unsigned)(ks * 48) * 20 + b4 * 4;
        const float* wp = SLAB + (unsigned)(ks * 48) * 64 + ml * 4;
#pragma unroll 8
        for (int kk = 0; kk < 48; ++kk) {
          float4 xv = *(const float4*)(xp + kk * 20);
          float4 wv = *(const float4*)(wp + kk * 64);
          FMA16V(a0, a1, a2, a3, xv, wv);
        }
      }
      __syncthreads();  // xah dead -> red
      {
        float* rp = red + (unsigned)(ks * 64 + ml * 4 + b4) * 20;
        *(float4*)(rp + 0) = a0; *(float4*)(rp + 4) = a1;
        *(float4*)(rp + 8) = a2; *(float4*)(rp + 12) = a3;
      }
      __syncthreads();
      if (tid < 256) {
        int m2 = tid & 15, bl = tid >> 4;
        int t2 = m2 * 4 + (bl >> 2), bs = bl & 3;
        float4 gate = {0,0,0,0};
#pragma unroll
        for (int k2 = 0; k2 < 8; ++k2) {
          float4 rr = *(const float4*)(red + (unsigned)(k2 * 64 + t2) * 20 + bs * 4);
          gate.x += rr.x; gate.y += rr.y; gate.z += rr.z; gate.w += rr.w;
        }
        float gi = gate.x + bsE.x, gf = gate.y + bsE.y;
        float gg = gate.z + bsE.z, go = gate.w + bsE.w;
        float cn = fast_sig(gf) * c_reg + fast_sig(gi) * fast_tanh(gg);
        float hn = fast_sig(go) * fast_tanh(cn);
        c_reg = cn;
        unsigned m = mt * 16 + m2;
        st1_sc1(ws + OFF_HE + (unsigned)wr2 * 65536 + (unsigned)grp * 4096 + m * 16 + bl, hn);
        st1_sc1(Xe + ((unsigned)(b0 + bl) * 64 + t) * 256 + m, hn);
        hcs[bl * 32 + m2] = hn;
        hcs[bl * 32 + 16 + m2] = cn;
      }
      __syncthreads();
      {  // S atomics: 2 batches per thread
        int j = tid & 63, wq = tid >> 6;
#pragma unroll
        for (int e2 = 0; e2 < 2; ++e2) {
          int bl2 = wq * 2 + e2;
          const float* hp = hcs + bl2 * 32;
          float s = 0.f;
#pragma unroll
          for (int q = 0; q < 4; ++q) {
            s += dot4(*(const float4*)(hp + q * 4), whc[q]);
            s += dot4(*(const float4*)(hp + 16 + q * 4), whc[4 + q]);
          }
          atomic_add_sc1(ws + OFF_SB + (unsigned)wr2 * 16384 + (unsigned)(b0 + bl2) * 64 + j, s);
        }
      }
    }
    group_barrier(barp, barn);
  }

  // ---- fill Xe row into regs: thread (m = tid&255, half = tid>>8) holds t = half*32 .. +31
  float xe[32];
  {
    int m = tid & 255, half = tid >> 8;
    const float* xb = Xe + (unsigned)bid * 16384 + (unsigned)(half * 32) * 256 + m;
#pragma unroll
    for (int g8 = 0; g8 < 4; ++g8) {
      ld8s_sc1(xe[g8*8+0], xe[g8*8+1], xe[g8*8+2], xe[g8*8+3],
               xe[g8*8+4], xe[g8*8+5], xe[g8*8+6], xe[g8*8+7],
               xb + (g8*8+0)*256, xb + (g8*8+1)*256, xb + (g8*8+2)*256,
               xb + (g8*8+3)*256, xb + (g8*8+4)*256, xb + (g8*8+5)*256,
               xb + (g8*8+6)*256, xb + (g8*8+7)*256);
    }
  }

  // ---- decoder one-time staging ----
  float* vd_s   = PER;
  float* wbt_s  = PER + 256;
  float* bsum_d = PER + 520;
  float* wihd_s = PER + 584;
  float* wudT   = SLAB + 16384;   // [32][256] col-major WU_d slice
  __syncthreads();
  {
    // decoder weight slab: SLAB[k*64 + r], k < 256
    int r = tid & 63, kq = tid >> 6;
    int grow = (r & 3) * 256 + mt * 16 + (r >> 2);
#pragma unroll 4
    for (int q = 0; q < 8; ++q) {
      int k = kq * 32 + q * 4;
      float4 wv = *(const float4*)(Whh_d + grow * 256 + k);
      SLAB[(k + 0) * 64 + r] = wv.x; SLAB[(k + 1) * 64 + r] = wv.y;
      SLAB[(k + 2) * 64 + r] = wv.z; SLAB[(k + 3) * 64 + r] = wv.w;
    }
    {
      int j = tid & 255, half = tid >> 8;
#pragma unroll
      for (int i = 0; i < 16; ++i) {
        int c = half * 16 + i;
        int col = (c < 16) ? (mt * 16 + c) : (256 + mt * 16 + (c - 16));
        wudT[c * 256 + j] = WUd[(unsigned)j * 768 + col];
      }
    }
    if (tid < 256) vd_s[tid] = vd[tid];
    if (tid < 257) wbt_s[tid] = wbt[tid];
    if (tid < 64) {
      int g = tid >> 4, m2 = tid & 15, m = mt * 16 + m2;
      bsum_d[tid] = bih_d[g * 256 + m] + bhh_d[g * 256 + m];
      wihd_s[tid] = Wih_d[g * 256 + m];
    }
  }
  __syncthreads();

  // ---------------- P2: XeWt[bid][j][t'] = sum_k Xe[bid][t'][k] * WU_d[j][512+k]
  {
    float* XeT = SCR;          // [64][64]
    float* Wdc = SCR + 4096;   // [64][128]
    int tt2 = tid & 15, jq = tid >> 4;       // jq 0..31
    int m = tid & 255, half = tid >> 8, kk_m = m & 63;
    for (int jc = 0; jc < 2; ++jc) {
      float4 c0 = {0,0,0,0}, c1 = {0,0,0,0}, c2 = {0,0,0,0}, c3 = {0,0,0,0};
      for (int kc = 0; kc < 4; ++kc) {
        __syncthreads();
        if ((m >> 6) == kc) {
#pragma unroll
          for (int t4 = 0; t4 < 8; ++t4) {
            float4 v = { xe[t4*4+0], xe[t4*4+1], xe[t4*4+2], xe[t4*4+3] };
            *(float4*)(XeT + kk_m * 64 + half * 32 + t4 * 4) = v;
          }
        }
        {
          int jj = tid >> 2, k16 = (tid & 3) * 16;
          const float* src = WUd + (unsigned)(jc * 128 + jj) * 768 + 512 + kc * 64 + k16;
#pragma unroll
          for (int s4 = 0; s4 < 4; ++s4) {
            float4 wv = *(const float4*)(src + s4 * 4);
            Wdc[(k16 + s4*4 + 0) * 128 + jj] = wv.x;
            Wdc[(k16 + s4*4 + 1) * 128 + jj] = wv.y;
            Wdc[(k16 + s4*4 + 2) * 128 + jj] = wv.z;
            Wdc[(k16 + s4*4 + 3) * 128 + jj] = wv.w;
          }
        }
        __syncthreads();
#pragma unroll 8
        for (int kk = 0; kk < 64; ++kk) {
          float4 xv = *(const float4*)(XeT + kk * 64 + tt2 * 4);
          float4 wv = *(const float4*)(Wdc + kk * 128 + jq * 4);
          FMA16V(c0, c1, c2, c3, wv, xv);
        }
      }
      int jb = jc * 128 + jq * 4;
      *(float4*)(XeWt + ((unsigned)bid * 256 + jb + 0) * 64 + tt2 * 4) = c0;
      *(float4*)(XeWt + ((unsigned)bid * 256 + jb + 1) * 64 + tt2 * 4) = c1;
      *(float4*)(XeWt + ((unsigned)bid * 256 + jb + 2) * 64 + tt2 * 4) = c2;
      *(float4*)(XeWt + ((unsigned)bid * 256 + jb + 3) * 64 + tt2 * 4) = c3;
    }
    __syncthreads();
  }

  // hoist decoder attention weights + bias into regs
  float wreg[32];
#pragma unroll
  for (int c = 0; c < 32; ++c) wreg[c] = wudT[c * 256 + (tid & 255)];
  float4 bsD = {0,0,0,0}, wiD = {0,0,0,0};
  {
    int m2 = tid & 15;
    bsD.x = bsum_d[m2]; bsD.y = bsum_d[16 + m2]; bsD.z = bsum_d[32 + m2]; bsD.w = bsum_d[48 + m2];
    wiD.x = wihd_s[m2]; wiD.y = wihd_s[16 + m2]; wiD.z = wihd_s[32 + m2]; wiD.w = wihd_s[48 + m2];
  }
  float cd_reg = 0.f;

  // ================ DECODER: 63 steps ================
  for (int t = 0; t < 63; ++t) {
    const int rd = t & 1, wr2 = (t + 1) & 1;
    // ---- DA: temporal attention + ctx + y_tilde (+ prefetch h into hT)
    {
      float* Sdj  = SCR;         // [256]
      float* lp   = SCR + 256;   // [8][64]
      float* beta = SCR + 768;   // [64]
      float* r8   = SCR + 832;   // [8]
      float* ctxp = SCR + 840;   // [2][256] -> 840..1352
      float* hT   = SCR + 2048;  // [256][20] -> 2048..7168
      {
        int kh = tid >> 2, i4 = (tid & 3) * 4;
        const float* hb = ws + OFF_HD + (unsigned)rd * 65536 + (unsigned)grp * 4096;
        float4 h0, h1, sv;
        ld1q_nw(h0, hb + kh * 16 + i4);
        ld1q_nw(h1, hb + (128 + kh) * 16 + i4);
        float* sp = ws + OFF_SDB + (unsigned)rd * 65536 + (unsigned)bid * 256 + tid * 4;
        if (tid < 64) ld1q_nw(sv, sp);
        vm0();
        *(float4*)(hT + kh * 20 + i4) = h0;
        *(float4*)(hT + (128 + kh) * 20 + i4) = h1;
        if (tid < 64) {
          st1_sc1(sp + 0, 0.f); st1_sc1(sp + 1, 0.f);
          st1_sc1(sp + 2, 0.f); st1_sc1(sp + 3, 0.f);
          *(float4*)(Sdj + tid * 4) = sv;
        }
      }
      __syncthreads();
      {
        int tq = tid & 63, q = tid >> 6;
        const float* xew = XeWt + (unsigned)bid * 16384 + tq;
        float l = 0.f;
#pragma unroll 8
        for (int jj = 0; jj < 32; ++jj) {
          int j = q * 32 + jj;
          l += vd_s[j] * fast_tanh(xew[j << 6] + Sdj[j]);
        }
        lp[q * 64 + tq] = l;
      }
      __syncthreads();
      if (tid < 64) {
        float lv = 0.f;
#pragma unroll
        for (int q = 0; q < 8; ++q) lv += lp[q * 64 + tid];
        float mx = wave_max(lv);
        float ex = __expf(lv - mx);
        float sw = wave_sum(ex);
        beta[tid] = ex / sw;
      }
      __syncthreads();
      {
        int m = tid & 255, half = tid >> 8;
        float acc = 0.f;
#pragma unroll
        for (int tt = 0; tt < 32; ++tt) acc += beta[half * 32 + tt] * xe[tt];
        ctxp[half * 256 + m] = acc;
      }
      __syncthreads();
      if (tid < 256) {
        float ctx = ctxp[tid] + ctxp[256 + tid];
        st1_sc1(ws + OFF_CTX + (unsigned)bid * 256 + tid, ctx);
        float yp = ctx * wbt_s[1 + tid];
        float swv = wave_sum(yp);
        int lane = tid & 63, wid = tid >> 6;
        if (lane == 0) r8[wid] = swv;
      }
      __syncthreads();
      if (tid == 0) {
        float yt = wbt_s[0] * in[bid * 8256 + t * 129 + 128] + r8[0] + r8[1] + r8[2] + r8[3];
        st1_sc1(ws + OFF_YT + bid, yt);
      }
    }
    group_barrier(barp, barn);

    // ---- DB: decoder gates GEMM (K=256, h already staged) + pointwise + Sd atomics
    {
      float* hT  = SCR + 2048;     // staged in DA
      float* red = SCR;            // [512][20] alias (written after k-loop)
      float* hcs = SCR + 10240;    // [16][32]
      float yt_reg = ld1s_sc1(ws + OFF_YT + b0 + ((tid >> 4) & 15));
      const int ks = tid >> 6, ml = (tid >> 2) & 15, b4 = tid & 3;
      float4 a0 = {0,0,0,0}, a1 = {0,0,0,0}, a2 = {0,0,0,0}, a3 = {0,0,0,0};
      {
        const float* xp = hT + (unsigned)(ks * 32) * 20 + b4 * 4;
        const float* wp = SLAB + (unsigned)(ks * 32) * 64 + ml * 4;
#pragma unroll 8
        for (int kk = 0; kk < 32; ++kk) {
          float4 xv = *(const float4*)(xp + kk * 20);
          float4 wv = *(const float4*)(wp + kk * 64);
          FMA16V(a0, a1, a2, a3, xv, wv);
        }
      }
      __syncthreads();
      {
        float* rp = red + (unsigned)(ks * 64 + ml * 4 + b4) * 20;
        *(float4*)(rp + 0) = a0; *(float4*)(rp + 4) = a1;
        *(float4*)(rp + 8) = a2; *(float4*)(rp + 12) = a3;
      }
      __syncthreads();
      if (tid < 256) {
        int m2 = tid & 15, bl = tid >> 4;
        int t2 = m2 * 4 + (bl >> 2), bs = bl & 3;
        float4 gate = {0,0,0,0};
#pragma unroll
        for (int k2 = 0; k2 < 8; ++k2) {
          float4 rr = *(const float4*)(red + (unsigned)(k2 * 64 + t2) * 20 + bs * 4);
          gate.x += rr.x; gate.y += rr.y; gate.z += rr.z; gate.w += rr.w;
        }
        float gi = gate.x + yt_reg * wiD.x + bsD.x;
        float gf = gate.y + yt_reg * wiD.y + bsD.y;
        float gg = gate.z + yt_reg * wiD.z + bsD.z;
        float go = gate.w + yt_reg * wiD.w + bsD.w;
        float cn = fast_sig(gf) * cd_reg + fast_sig(gi) * fast_tanh(gg);
        float hn = fast_sig(go) * fast_tanh(cn);
        cd_reg = cn;
        unsigned m = mt * 16 + m2;
        st1_sc1(ws + OFF_HD + (unsigned)wr2 * 65536 + (unsigned)grp * 4096 + m * 16 + bl, hn);
        hcs[bl * 32 + m2] = hn;
        hcs[bl * 32 + 16 + m2] = cn;
      }
      __syncthreads();
      {  // Sd atomics: 8 batches per thread, j = tid&255
        int j = tid & 255, half = tid >> 8;
#pragma unroll
        for (int e2 = 0; e2 < 8; ++e2) {
          int bl2 = half * 8 + e2;
          const float* hp = hcs + bl2 * 32;
          float s = 0.f;
#pragma unroll
          for (int c = 0; c < 16; ++c) s += hp[c] * wreg[c];
#pragma unroll
          for (int c = 0; c < 16; ++c) s += hp[16 + c] * wreg[16 + c];
          atomic_add_sc1(ws + OFF_SDB + (unsigned)wr2 * 65536 + (unsigned)(b0 + bl2) * 256 + j, s);
        }
      }
    }
    group_barrier(barp, barn);
  }

  // ---------------- FINAL: hidden = [h_d, ctx] @ Wb_W.T + Wb_b; y = hidden @ vb_W.T + vb_b
  {
    float* hsf  = SCR;          // [16][516]
    float* hid2 = SCR + 8256;   // [2][16][17]
    {
      // h-part (transposed source): lin 0..1023 -> k = lin>>2, i = lin&3
      int l0 = tid * 2, l1 = tid * 2 + 1;
      int k0 = l0 >> 2, i0 = l0 & 3, k1 = l1 >> 2, i1 = l1 & 3;
      const float* hb = ws + OFF_HD + 65536u + (unsigned)grp * 4096;
      // ctx part: bl = lin>>6, c = (lin&63)*4
      int bl0 = l0 >> 6, c0 = (l0 & 63) * 4, bl1 = l1 >> 6, c1 = (l1 & 63) * 4;
      float4 qa, qb, qc, qd;
      ld1q_nw(qa, hb + k0 * 16 + i0 * 4);
      ld1q_nw(qb, hb + k1 * 16 + i1 * 4);
      ld1q_nw(qc, ws + OFF_CTX + (unsigned)(b0 + bl0) * 256 + c0);
      ld1q_nw(qd, ws + OFF_CTX + (unsigned)(b0 + bl1) * 256 + c1);
      vm0();
      hsf[(i0 * 4 + 0) * 516 + k0] = qa.x; hsf[(i0 * 4 + 1) * 516 + k0] = qa.y;
      hsf[(i0 * 4 + 2) * 516 + k0] = qa.z; hsf[(i0 * 4 + 3) * 516 + k0] = qa.w;
      hsf[(i1 * 4 + 0) * 516 + k1] = qb.x; hsf[(i1 * 4 + 1) * 516 + k1] = qb.y;
      hsf[(i1 * 4 + 2) * 516 + k1] = qb.z; hsf[(i1 * 4 + 3) * 516 + k1] = qb.w;
      *(float4*)(hsf + bl0 * 516 + 256 + c0) = qc;
      *(float4*)(hsf + bl1 * 516 + 256 + c1) = qd;
    }
    __syncthreads();
    int bl = tid & 15, p4 = (tid >> 4) & 15, half = tid >> 8;
    int row = mt * 16 + p4;
    const float* wrow = WbW + (unsigned)row * 512 + half * 256;
    const float* hp = hsf + bl * 516 + half * 256;
    float acc = half ? 0.f : Wbb[row];
#pragma unroll 8
    for (int q = 0; q < 64; ++q)
      acc += dot4(*(const float4*)(hp + q * 4), *(const float4*)(wrow + q * 4));
    hid2[half * 272 + bl * 17 + p4] = acc;
    __syncthreads();
    if (tid < 16) {
      float s = 0.f;
#pragma unroll
      for (int p = 0; p < 16; ++p)
        s += (hid2[tid * 17 + p] + hid2[272 + tid * 17 + p]) * vbW[mt * 16 + p];
      if (mt == 0) s += vbb[0];
      atomicAdd(&out[b0 + tid], s);
    }
  }
}

extern "C" void kernel_launch(void* const* d_in, const int* in_sizes, int n_in,
                              void* d_out, int out_size, void* d_ws, size_t ws_size,
                              hipStream_t stream) {
  (void)in_sizes; (void)n_in; (void)out_size; (void)ws_size;
  const float* in    = (const float*)d_in[0];
  const float* WUe   = (const float*)d_in[1];
  const float* ve    = (const float*)d_in[2];
  const float* Wih_e = (const float*)d_in[3];
  const float* Whh_e = (const float*)d_in[4];
  const float* bih_e = (const float*)d_in[5];
  const float* bhh_e = (const float*)d_in[6];
  const float* WUd   = (const float*)d_in[7];
  const float* vd    = (const float*)d_in[8];
  const float* wbt   = (const float*)d_in[9];
  const float* Wih_d = (const float*)d_in[10];
  const float* Whh_d = (const float*)d_in[11];
  const float* bih_d = (const float*)d_in[12];
  const float* bhh_d = (const float*)d_in[13];
  const float* WbW   = (const float*)d_in[14];
  const float* Wbb   = (const float*)d_in[15];
  const float* vbW   = (const float*)d_in[16];
  const float* vbb   = (const float*)d_in[17];
  float* ws  = (float*)d_ws;
  float* out = (float*)d_out;

  (void)hipFuncSetAttribute((const void*)darnn_main,
                            hipFuncAttributeMaxDynamicSharedMemorySize, SMEM_BYTES);
  hipLaunchKernelGGL(darnn_init, dim3(1024), dim3(256), 0, stream, ws, out);
  hipLaunchKernelGGL(darnn_main, dim3(256), dim3(512), SMEM_BYTES, stream,
                     in, WUe, ve, Wih_e, Whh_e, bih_e, bhh_e,
                     WUd, vd, wbt, Wih_d, Whh_d, bih_d, bhh_d,
                     WbW, Wbb, vbW, vbb, ws, out);
}

// Round 7
// 1389.223 us; speedup vs baseline: 1.0977x; 1.0977x over previous
//
#include <hip/hip_runtime.h>
#include <math.h>

// Problem dims: B=256, T=64, N=128, M=256, P=256, YD=1
// 256 blocks x 512 threads (8 waves). Group = 16 blocks = 16 batches; block role mt = m-tile.
// Split arrive/wait barriers: barrier latency hidden behind h-part GEMM.

// Workspace layout (float offsets)
#define OFF_XWT   0u          // [256][64][128]  XWt[b][j][n]   (block-local)
#define OFF_XEWT  2097152u    // [256][256][64]  XeWt[b][j][t'] (block-local)
#define OFF_XE    6291456u    // [256][64][256]  Xe[b][t][m]    (sc1 w, sc1 r once)
#define OFF_HE    10485760u   // [2][16][256][16] h_e transposed: [buf][grp][k][bl]
#define OFF_HD    10616832u   // [2][16][256][16] h_d transposed
#define OFF_SB    10747904u   // [2][256][64]    S accum        (atomic add / sc1 r+zero)
#define OFF_SDB   10780672u   // [2][256][256]   Sd accum       (atomic add / sc1 r+zero)
#define OFF_XA    10911744u   // [16][128][16]   x*alpha transposed: [grp][n][bl]
#define OFF_CTX   10944512u   // [256][256]      ctx            (sc1 w/r)
#define OFF_YT    11010048u   // [256]           y_tilde        (sc1 w/r)
#define OFF_BAR   11010304u   // 16 groups x 32 u32
#define WS_END    11010816u

// LDS (floats): SLAB (weights, persistent) | PER (small persistent) | SCR (per-phase)
#define SLAB_F 24576
#define PER_F  2432
#define SCR_F  12288
#define SMEM_F (SLAB_F + PER_F + SCR_F)
#define SMEM_BYTES (SMEM_F * 4)   // 157184 B <= 160 KB

__device__ __forceinline__ float fast_tanh(float x) {
  float xc = fminf(15.f, fmaxf(-15.f, x));
  float e = __expf(2.f * xc);
  return 1.f - 2.f * __builtin_amdgcn_rcpf(e + 1.f);
}
__device__ __forceinline__ float fast_sig(float x) {
  float xc = fminf(30.f, fmaxf(-30.f, x));
  return __builtin_amdgcn_rcpf(1.f + __expf(-xc));
}
__device__ __forceinline__ float wave_max(float v) {
#pragma unroll
  for (int o = 32; o; o >>= 1) v = fmaxf(v, __shfl_xor(v, o));
  return v;
}
__device__ __forceinline__ float wave_sum(float v) {
#pragma unroll
  for (int o = 32; o; o >>= 1) v += __shfl_xor(v, o);
  return v;
}
__device__ __forceinline__ float dot4(float4 a, float4 b) {
  return a.x*b.x + a.y*b.y + a.z*b.z + a.w*b.w;
}

// ---- device-scope (sc1) coherent helpers ----
// float4 only as ASM OUTPUT ("=&v"); struct inputs in "v" don't compile.
__device__ __forceinline__ void st1_sc1(float* p, float v) {
  asm volatile("global_store_dword %0, %1, off sc1" :: "v"(p), "v"(v) : "memory");
}
__device__ __forceinline__ void ld1q_sc1(float4& a, const float* pa) {
  asm volatile("global_load_dwordx4 %0, %1, off sc1\n\ts_waitcnt vmcnt(0)"
               : "=&v"(a) : "v"(pa) : "memory");
}
__device__ __forceinline__ void ld1q_nw(float4& a, const float* pa) {
  asm volatile("global_load_dwordx4 %0, %1, off sc1"
               : "=&v"(a) : "v"(pa) : "memory");
}
__device__ __forceinline__ void vm0() {
  asm volatile("s_waitcnt vmcnt(0)" ::: "memory");
}
__device__ __forceinline__ float ld1s_sc1(const float* p) {
  float v;
  asm volatile("global_load_dword %0, %1, off sc1\n\ts_waitcnt vmcnt(0)"
               : "=&v"(v) : "v"(p) : "memory");
  return v;
}
__device__ __forceinline__ void ld8s_sc1(
    float& a0,float& a1,float& a2,float& a3,float& a4,float& a5,float& a6,float& a7,
    const float* p0,const float* p1,const float* p2,const float* p3,
    const float* p4,const float* p5,const float* p6,const float* p7) {
  asm volatile(
      "global_load_dword %0, %8, off sc1\n\t"
      "global_load_dword %1, %9, off sc1\n\t"
      "global_load_dword %2, %10, off sc1\n\t"
      "global_load_dword %3, %11, off sc1\n\t"
      "global_load_dword %4, %12, off sc1\n\t"
      "global_load_dword %5, %13, off sc1\n\t"
      "global_load_dword %6, %14, off sc1\n\t"
      "global_load_dword %7, %15, off sc1\n\t"
      "s_waitcnt vmcnt(0)"
      : "=&v"(a0),"=&v"(a1),"=&v"(a2),"=&v"(a3),
        "=&v"(a4),"=&v"(a5),"=&v"(a6),"=&v"(a7)
      : "v"(p0),"v"(p1),"v"(p2),"v"(p3),"v"(p4),"v"(p5),"v"(p6),"v"(p7)
      : "memory");
}
__device__ __forceinline__ void atomic_add_sc1(float* p, float v) {
  asm volatile("global_atomic_add_f32 %0, %1, off sc1" :: "v"(p), "v"(v) : "memory");
}

// a_i (batch b4*4+i, gates.xyzw) += xv_i * wv
#define FMA16V(a0,a1,a2,a3,xv,wv) \
  a0.x += xv.x*wv.x; a0.y += xv.x*wv.y; a0.z += xv.x*wv.z; a0.w += xv.x*wv.w; \
  a1.x += xv.y*wv.x; a1.y += xv.y*wv.y; a1.z += xv.y*wv.z; a1.w += xv.y*wv.w; \
  a2.x += xv.z*wv.x; a2.y += xv.z*wv.y; a2.z += xv.z*wv.z; a2.w += xv.z*wv.w; \
  a3.x += xv.w*wv.x; a3.y += xv.w*wv.y; a3.z += xv.w*wv.z; a3.w += xv.w*wv.w;

// Split fence-free group barrier: monotonic counter, relaxed agent atomics.
// arrive: drain this block's stores, then one atomic increment (no wait).
// wait:   poll until all 16 blocks of the group arrived the event.
__device__ __forceinline__ void bar_arrive(unsigned* bar) {
  asm volatile("s_waitcnt vmcnt(0)" ::: "memory");
  __syncthreads();
  if (threadIdx.x == 0)
    __hip_atomic_fetch_add(bar, 1u, __ATOMIC_RELAXED, __HIP_MEMORY_SCOPE_AGENT);
}
__device__ __forceinline__ void bar_wait(unsigned* bar, unsigned target) {
  if (threadIdx.x == 0) {
    unsigned cur;
    do {
      cur = __hip_atomic_load(bar, __ATOMIC_RELAXED, __HIP_MEMORY_SCOPE_AGENT);
    } while (cur < target);
  }
  __syncthreads();
}

__global__ void darnn_init(float* __restrict__ ws, float* __restrict__ out) {
  unsigned i = blockIdx.x * 256u + threadIdx.x;
  const unsigned span = WS_END - OFF_HE;
  for (unsigned idx = i; idx < span; idx += gridDim.x * 256u) ws[OFF_HE + idx] = 0.f;
  if (i < 256u) out[i] = 0.f;
}

__global__ __launch_bounds__(512, 2) void darnn_main(
    const float* __restrict__ in,   const float* __restrict__ WUe,   const float* __restrict__ ve,
    const float* __restrict__ Wih_e,const float* __restrict__ Whh_e,
    const float* __restrict__ bih_e,const float* __restrict__ bhh_e,
    const float* __restrict__ WUd,  const float* __restrict__ vd,
    const float* __restrict__ wbt,  const float* __restrict__ Wih_d,
    const float* __restrict__ Whh_d,const float* __restrict__ bih_d, const float* __restrict__ bhh_d,
    const float* __restrict__ WbW,  const float* __restrict__ Wbb,
    const float* __restrict__ vbW,  const float* __restrict__ vbb,
    float* __restrict__ ws, float* __restrict__ out)
{
  extern __shared__ __align__(16) float sm[];
  float* SLAB = sm;
  float* PER  = sm + SLAB_F;
  float* SCR  = sm + SLAB_F + PER_F;
  const int tid = threadIdx.x;
  const int bid = blockIdx.x;
  const int grp = bid >> 4;
  const int mt  = bid & 15;
  const int b0  = grp << 4;

  float* XWt  = ws + OFF_XWT;
  float* XeWt = ws + OFF_XEWT;
  float* Xe   = ws + OFF_XE;
  unsigned* barp = (unsigned*)(ws + OFF_BAR) + grp * 32;
  unsigned barn = 0;

  // PER (encoder): wue_s [64][36]; ve_s [64] @2304; bsum_e [64] @2368
  float* wue_s  = PER;
  float* ve_s   = PER + 2304;
  float* bsum_e = PER + 2368;

  // ---- one-time encoder staging ----
  {
    int r = tid & 63, kq = tid >> 6;
    int grow = (r & 3) * 256 + mt * 16 + (r >> 2);
#pragma unroll 4
    for (int q = 0; q < 12; ++q) {
      int k = kq * 48 + q * 4;
      float4 wv = (k < 128) ? *(const float4*)(Wih_e + grow * 128 + k)
                            : *(const float4*)(Whh_e + grow * 256 + (k - 128));
      SLAB[(k + 0) * 64 + r] = wv.x; SLAB[(k + 1) * 64 + r] = wv.y;
      SLAB[(k + 2) * 64 + r] = wv.z; SLAB[(k + 3) * 64 + r] = wv.w;
    }
    {
      int lin = tid * 4;
      int j = lin >> 5, c0 = lin & 31;
      int col = (c0 < 16) ? (mt * 16 + c0) : (256 + mt * 16 + (c0 - 16));
      float4 wv = *(const float4*)(WUe + j * 576 + col);
      *(float4*)(wue_s + j * 36 + c0) = wv;
    }
    if (tid < 64) {
      ve_s[tid] = ve[tid];
      int g = tid >> 4, m2 = tid & 15, m = mt * 16 + m2;
      bsum_e[tid] = bih_e[g * 256 + m] + bhh_e[g * 256 + m];
    }
  }

  // ---------------- P1: XWt[bid][j][n] = sum_k X[bid][k][n] * WU_e[j][512+k]
  {
    float* Xs = SCR;  // [128][68]
    const float* Xb = in + bid * 8256;
    __syncthreads();
    for (int it = 0; it < 16; ++it) {
      int lin = tid + it * 512;
      int k = lin >> 7, n = lin & 127;
      Xs[n * 68 + k] = Xb[k * 129 + n];
    }
    __syncthreads();
    int j = tid & 63, nh = tid >> 6;
    float acc[16];
#pragma unroll
    for (int i = 0; i < 16; ++i) acc[i] = 0.f;
    const float* wrow = WUe + j * 576 + 512;
    for (int kc = 0; kc < 4; ++kc) {
      float4 w0 = *(const float4*)(wrow + kc * 16 + 0);
      float4 w1 = *(const float4*)(wrow + kc * 16 + 4);
      float4 w2 = *(const float4*)(wrow + kc * 16 + 8);
      float4 w3 = *(const float4*)(wrow + kc * 16 + 12);
#pragma unroll
      for (int ni = 0; ni < 16; ++ni) {
        const float* xp = Xs + (nh * 16 + ni) * 68 + kc * 16;
        acc[ni] += dot4(*(const float4*)(xp + 0),  w0) + dot4(*(const float4*)(xp + 4),  w1)
                 + dot4(*(const float4*)(xp + 8),  w2) + dot4(*(const float4*)(xp + 12), w3);
      }
    }
    float* dst = XWt + bid * 8192 + j * 128 + nh * 16;
#pragma unroll
    for (int ni = 0; ni < 16; ++ni) dst[ni] = acc[ni];
    __syncthreads();
  }

  // hoist attention weights + per-thread XWt slice into regs (constant over t)
  float4 whc[8];
#pragma unroll
  for (int q = 0; q < 8; ++q) whc[q] = *(const float4*)(wue_s + (tid & 63) * 36 + q * 4);
  float4 bsE = {0,0,0,0};
  {
    int m2 = tid & 15;
    bsE.x = bsum_e[m2]; bsE.y = bsum_e[16 + m2];
    bsE.z = bsum_e[32 + m2]; bsE.w = bsum_e[48 + m2];
  }
  float xwreg[16];
  {
    int n = tid & 127, jh = tid >> 7;
    const float* xwp = XWt + bid * 8192 + n;
#pragma unroll
    for (int jj = 0; jj < 16; ++jj) xwreg[jj] = xwp[(jh * 16 + jj) << 7];
  }
  float c_reg = 0.f;   // c-state for thread (m2 = tid&15, bl = (tid>>4)&15), tid<256

  // ================ ENCODER: 64 steps ================
  for (int t = 0; t < 64; ++t) {
    const int rd = t & 1, wr2 = (t + 1) & 1;
    float4 h0, h1;   // h prefetch (committed to LDS after arrive)
    // ---- EA: wait prev publish; attention for b = bid
    {
      float* Sj  = SCR;          // [64]
      float* Eh  = SCR + 64;     // [4][128]
      float* r8  = SCR + 576;    // [8]
      bar_wait(barp, barn);      // S(rd), h(rd) visible (no-op at t=0)
      {
        int kh = tid >> 2, i4 = (tid & 3) * 4;
        const float* hb = ws + OFF_HE + (unsigned)rd * 65536 + (unsigned)grp * 4096;
        ld1q_nw(h0, hb + kh * 16 + i4);
        ld1q_nw(h1, hb + (128 + kh) * 16 + i4);
        if (tid < 16) {
          float* sp = ws + OFF_SB + (unsigned)rd * 16384 + (unsigned)bid * 64 + tid * 4;
          float4 sv;
          ld1q_sc1(sv, sp);      // waits vmcnt(0): h loads also land (harmless)
          st1_sc1(sp + 0, 0.f); st1_sc1(sp + 1, 0.f);
          st1_sc1(sp + 2, 0.f); st1_sc1(sp + 3, 0.f);
          *(float4*)(Sj + tid * 4) = sv;
        }
      }
      __syncthreads();
      {
        int n = tid & 127;
        float e = 0.f;
        int jb = (tid >> 7) * 16;
#pragma unroll
        for (int jj = 0; jj < 16; ++jj)
          e += ve_s[jb + jj] * fast_tanh(xwreg[jj] + Sj[jb + jj]);
        Eh[(tid >> 7) * 128 + n] = e;
      }
      __syncthreads();
      int lane = tid & 63, wid = tid >> 6;
      float En = (tid < 128) ? (Eh[tid] + Eh[128 + tid] + Eh[256 + tid] + Eh[384 + tid]) : -1e30f;
      float mx = wave_max(En);
      if (tid < 128 && lane == 0) r8[wid] = mx;
      __syncthreads();
      mx = fmaxf(r8[0], r8[1]);
      float ex = (tid < 128) ? __expf(En - mx) : 0.f;
      float sw = wave_sum(ex);
      if (tid < 128 && lane == 0) r8[4 + wid] = sw;
      __syncthreads();
      float tot = r8[4] + r8[5];
      if (tid < 128)
        st1_sc1(ws + OFF_XA + (unsigned)grp * 2048 + tid * 16 + mt,
                in[bid * 8256 + t * 129 + tid] * (ex / tot));
    }
    barn += 16;
    bar_arrive(barp);            // drains XA (and h prefetch regs already landed)

    // ---- EB: h-part GEMM runs BEFORE waiting (hides barrier latency)
    {
      float* xah = SCR + 1024;     // [384][20]
      float* red = SCR;            // [512][20] alias (written after k-loops)
      float* hcs = SCR + 10240;    // [16][32]
      {  // commit h prefetch to LDS
        int kh = tid >> 2, i4 = (tid & 3) * 4;
        *(float4*)(xah + (128 + kh) * 20 + i4) = h0;
        *(float4*)(xah + (256 + kh) * 20 + i4) = h1;
      }
      __syncthreads();
      const int ks = tid >> 6, ml = (tid >> 2) & 15, b4 = tid & 3;
      float4 a0 = {0,0,0,0}, a1 = {0,0,0,0}, a2 = {0,0,0,0}, a3 = {0,0,0,0};
      {  // h-part: strip ks covers k = 128+ks*32 .. +31
        const float* xp = xah + (unsigned)(128 + ks * 32) * 20 + b4 * 4;
        const float* wp = SLAB + (unsigned)(128 + ks * 32) * 64 + ml * 4;
#pragma unroll 8
        for (int kk = 0; kk < 32; ++kk) {
          float4 xv = *(const float4*)(xp + kk * 20);
          float4 wv = *(const float4*)(wp + kk * 64);
          FMA16V(a0, a1, a2, a3, xv, wv);
        }
      }
      bar_wait(barp, barn);        // all XAs visible now
      {  // stage XA rows 0..127
        int k = tid >> 2, i4 = (tid & 3) * 4;
        float4 q;
        ld1q_sc1(q, ws + OFF_XA + (unsigned)grp * 2048 + k * 16 + i4);
        *(float4*)(xah + k * 20 + i4) = q;
      }
      __syncthreads();
      {  // x-part: strip ks covers k = ks*16 .. +15
        const float* xp = xah + (unsigned)(ks * 16) * 20 + b4 * 4;
        const float* wp = SLAB + (unsigned)(ks * 16) * 64 + ml * 4;
#pragma unroll 8
        for (int kk = 0; kk < 16; ++kk) {
          float4 xv = *(const float4*)(xp + kk * 20);
          float4 wv = *(const float4*)(wp + kk * 64);
          FMA16V(a0, a1, a2, a3, xv, wv);
        }
      }
      __syncthreads();  // xah dead -> red
      {
        float* rp = red + (unsigned)(ks * 64 + ml * 4 + b4) * 20;
        *(float4*)(rp + 0) = a0; *(float4*)(rp + 4) = a1;
        *(float4*)(rp + 8) = a2; *(float4*)(rp + 12) = a3;
      }
      __syncthreads();
      if (tid < 256) {
        int m2 = tid & 15, bl = tid >> 4;
        int t2 = m2 * 4 + (bl >> 2), bs = bl & 3;
        float4 gate = {0,0,0,0};
#pragma unroll
        for (int k2 = 0; k2 < 8; ++k2) {
          float4 rr = *(const float4*)(red + (unsigned)(k2 * 64 + t2) * 20 + bs * 4);
          gate.x += rr.x; gate.y += rr.y; gate.z += rr.z; gate.w += rr.w;
        }
        float gi = gate.x + bsE.x, gf = gate.y + bsE.y;
        float gg = gate.z + bsE.z, go = gate.w + bsE.w;
        float cn = fast_sig(gf) * c_reg + fast_sig(gi) * fast_tanh(gg);
        float hn = fast_sig(go) * fast_tanh(cn);
        c_reg = cn;
        unsigned m = mt * 16 + m2;
        st1_sc1(ws + OFF_HE + (unsigned)wr2 * 65536 + (unsigned)grp * 4096 + m * 16 + bl, hn);
        st1_sc1(Xe + ((unsigned)(b0 + bl) * 64 + t) * 256 + m, hn);
        hcs[bl * 32 + m2] = hn;
        hcs[bl * 32 + 16 + m2] = cn;
      }
      __syncthreads();
      {  // S atomics: 2 batches per thread
        int j = tid & 63, wq = tid >> 6;
#pragma unroll
        for (int e2 = 0; e2 < 2; ++e2) {
          int bl2 = wq * 2 + e2;
          const float* hp = hcs + bl2 * 32;
          float s = 0.f;
#pragma unroll
          for (int q = 0; q < 4; ++q) {
            s += dot4(*(const float4*)(hp + q * 4), whc[q]);
            s += dot4(*(const float4*)(hp + 16 + q * 4), whc[4 + q]);
          }
          atomic_add_sc1(ws + OFF_SB + (unsigned)wr2 * 16384 + (unsigned)(b0 + bl2) * 64 + j, s);
        }
      }
    }
    barn += 16;
    bar_arrive(barp);            // drains h, Xe, S atomics
  }
  bar_wait(barp, barn);          // all Xe published

  // ---- fill Xe row into regs: thread (m = tid&255, half = tid>>8) holds t = half*32 .. +31
  float xe[32];
  {
    int m = tid & 255, half = tid >> 8;
    const float* xb = Xe + (unsigned)bid * 16384 + (unsigned)(half * 32) * 256 + m;
#pragma unroll
    for (int g8 = 0; g8 < 4; ++g8) {
      ld8s_sc1(xe[g8*8+0], xe[g8*8+1], xe[g8*8+2], xe[g8*8+3],
               xe[g8*8+4], xe[g8*8+5], xe[g8*8+6], xe[g8*8+7],
               xb + (g8*8+0)*256, xb + (g8*8+1)*256, xb + (g8*8+2)*256,
               xb + (g8*8+3)*256, xb + (g8*8+4)*256, xb + (g8*8+5)*256,
               xb + (g8*8+6)*256, xb + (g8*8+7)*256);
    }
  }

  // ---- decoder one-time staging ----
  float* vd_s   = PER;
  float* wbt_s  = PER + 256;
  float* bsum_d = PER + 520;
  float* wihd_s = PER + 584;
  float* wudT   = SLAB + 16384;   // [32][256] col-major WU_d slice
  __syncthreads();
  {
    int r = tid & 63, kq = tid >> 6;
    int grow = (r & 3) * 256 + mt * 16 + (r >> 2);
#pragma unroll 4
    for (int q = 0; q < 8; ++q) {
      int k = kq * 32 + q * 4;
      float4 wv = *(const float4*)(Whh_d + grow * 256 + k);
      SLAB[(k + 0) * 64 + r] = wv.x; SLAB[(k + 1) * 64 + r] = wv.y;
      SLAB[(k + 2) * 64 + r] = wv.z; SLAB[(k + 3) * 64 + r] = wv.w;
    }
    {
      int j = tid & 255, half = tid >> 8;
#pragma unroll
      for (int i = 0; i < 16; ++i) {
        int c = half * 16 + i;
        int col = (c < 16) ? (mt * 16 + c) : (256 + mt * 16 + (c - 16));
        wudT[c * 256 + j] = WUd[(unsigned)j * 768 + col];
      }
    }
    if (tid < 256) vd_s[tid] = vd[tid];
    if (tid < 257) wbt_s[tid] = wbt[tid];
    if (tid < 64) {
      int g = tid >> 4, m2 = tid & 15, m = mt * 16 + m2;
      bsum_d[tid] = bih_d[g * 256 + m] + bhh_d[g * 256 + m];
      wihd_s[tid] = Wih_d[g * 256 + m];
    }
  }
  __syncthreads();

  // ---------------- P2: XeWt[bid][j][t'] = sum_k Xe[bid][t'][k] * WU_d[j][512+k]
  {
    float* XeT = SCR;          // [64][64]
    float* Wdc = SCR + 4096;   // [64][128]
    int tt2 = tid & 15, jq = tid >> 4;       // jq 0..31
    int m = tid & 255, half = tid >> 8, kk_m = m & 63;
    for (int jc = 0; jc < 2; ++jc) {
      float4 c0 = {0,0,0,0}, c1 = {0,0,0,0}, c2 = {0,0,0,0}, c3 = {0,0,0,0};
      for (int kc = 0; kc < 4; ++kc) {
        __syncthreads();
        if ((m >> 6) == kc) {
#pragma unroll
          for (int t4 = 0; t4 < 8; ++t4) {
            float4 v = { xe[t4*4+0], xe[t4*4+1], xe[t4*4+2], xe[t4*4+3] };
            *(float4*)(XeT + kk_m * 64 + half * 32 + t4 * 4) = v;
          }
        }
        {
          int jj = tid >> 2, k16 = (tid & 3) * 16;
          const float* src = WUd + (unsigned)(jc * 128 + jj) * 768 + 512 + kc * 64 + k16;
#pragma unroll
          for (int s4 = 0; s4 < 4; ++s4) {
            float4 wv = *(const float4*)(src + s4 * 4);
            Wdc[(k16 + s4*4 + 0) * 128 + jj] = wv.x;
            Wdc[(k16 + s4*4 + 1) * 128 + jj] = wv.y;
            Wdc[(k16 + s4*4 + 2) * 128 + jj] = wv.z;
            Wdc[(k16 + s4*4 + 3) * 128 + jj] = wv.w;
          }
        }
        __syncthreads();
#pragma unroll 8
        for (int kk = 0; kk < 64; ++kk) {
          float4 xv = *(const float4*)(XeT + kk * 64 + tt2 * 4);
          float4 wv = *(const float4*)(Wdc + kk * 128 + jq * 4);
          FMA16V(c0, c1, c2, c3, wv, xv);
        }
      }
      int jb = jc * 128 + jq * 4;
      *(float4*)(XeWt + ((unsigned)bid * 256 + jb + 0) * 64 + tt2 * 4) = c0;
      *(float4*)(XeWt + ((unsigned)bid * 256 + jb + 1) * 64 + tt2 * 4) = c1;
      *(float4*)(XeWt + ((unsigned)bid * 256 + jb + 2) * 64 + tt2 * 4) = c2;
      *(float4*)(XeWt + ((unsigned)bid * 256 + jb + 3) * 64 + tt2 * 4) = c3;
    }
    __syncthreads();
  }

  // hoist decoder attention weights + bias + per-thread XeWt slice into regs
  float wreg[32];
#pragma unroll
  for (int c = 0; c < 32; ++c) wreg[c] = wudT[c * 256 + (tid & 255)];
  float4 bsD = {0,0,0,0}, wiD = {0,0,0,0};
  {
    int m2 = tid & 15;
    bsD.x = bsum_d[m2]; bsD.y = bsum_d[16 + m2]; bsD.z = bsum_d[32 + m2]; bsD.w = bsum_d[48 + m2];
    wiD.x = wihd_s[m2]; wiD.y = wihd_s[16 + m2]; wiD.z = wihd_s[32 + m2]; wiD.w = wihd_s[48 + m2];
  }
  float xewreg[32];
  {
    int tq = tid & 63, q = tid >> 6;
    const float* xew = XeWt + (unsigned)bid * 16384 + tq;
#pragma unroll
    for (int jj = 0; jj < 32; ++jj) xewreg[jj] = xew[(q * 32 + jj) << 6];
  }
  float cd_reg = 0.f;

  // ================ DECODER: 63 steps ================
  for (int t = 0; t < 63; ++t) {
    const int rd = t & 1, wr2 = (t + 1) & 1;
    float4 h0, h1;
    // ---- DA: wait prev publish; temporal attention + ctx + y_tilde
    {
      float* Sdj  = SCR;         // [256]
      float* lp   = SCR + 256;   // [8][64]
      float* beta = SCR + 768;   // [64]
      float* r8   = SCR + 832;   // [8]
      float* ctxp = SCR + 840;   // [2][256]
      bar_wait(barp, barn);      // Sd(rd), h(rd) visible (no-op at t=0)
      {
        int kh = tid >> 2, i4 = (tid & 3) * 4;
        const float* hb = ws + OFF_HD + (unsigned)rd * 65536 + (unsigned)grp * 4096;
        ld1q_nw(h0, hb + kh * 16 + i4);
        ld1q_nw(h1, hb + (128 + kh) * 16 + i4);
        if (tid < 64) {
          float* sp = ws + OFF_SDB + (unsigned)rd * 65536 + (unsigned)bid * 256 + tid * 4;
          float4 sv;
          ld1q_sc1(sv, sp);
          st1_sc1(sp + 0, 0.f); st1_sc1(sp + 1, 0.f);
          st1_sc1(sp + 2, 0.f); st1_sc1(sp + 3, 0.f);
          *(float4*)(Sdj + tid * 4) = sv;
        }
      }
      __syncthreads();
      {
        int tq = tid & 63, q = tid >> 6;
        float l = 0.f;
#pragma unroll 8
        for (int jj = 0; jj < 32; ++jj) {
          int j = q * 32 + jj;
          l += vd_s[j] * fast_tanh(xewreg[jj] + Sdj[j]);
        }
        lp[q * 64 + tq] = l;
      }
      __syncthreads();
      if (tid < 64) {
        float lv = 0.f;
#pragma unroll
        for (int q = 0; q < 8; ++q) lv += lp[q * 64 + tid];
        float mx = wave_max(lv);
        float ex = __expf(lv - mx);
        float sw = wave_sum(ex);
        beta[tid] = ex / sw;
      }
      __syncthreads();
      {
        int m = tid & 255, half = tid >> 8;
        float acc = 0.f;
#pragma unroll
        for (int tt = 0; tt < 32; ++tt) acc += beta[half * 32 + tt] * xe[tt];
        ctxp[half * 256 + m] = acc;
      }
      __syncthreads();
      if (tid < 256) {
        float ctx = ctxp[tid] + ctxp[256 + tid];
        st1_sc1(ws + OFF_CTX + (unsigned)bid * 256 + tid, ctx);
        float yp = ctx * wbt_s[1 + tid];
        float swv = wave_sum(yp);
        int lane = tid & 63, wid = tid >> 6;
        if (lane == 0) r8[wid] = swv;
      }
      __syncthreads();
      if (tid == 0) {
        float yt = wbt_s[0] * in[bid * 8256 + t * 129 + 128] + r8[0] + r8[1] + r8[2] + r8[3];
        st1_sc1(ws + OFF_YT + bid, yt);
      }
    }
    barn += 16;
    bar_arrive(barp);            // drains ctx, yt

    // ---- DB: full K=256 GEMM + reduce BEFORE waiting (yt needed only by pointwise)
    {
      float* hT  = SCR + 2048;     // [256][20]
      float* red = SCR;            // [512][20] alias (written after k-loop)
      float* hcs = SCR + 10240;    // [16][32]
      {  // commit h prefetch to LDS
        int kh = tid >> 2, i4 = (tid & 3) * 4;
        *(float4*)(hT + kh * 20 + i4) = h0;
        *(float4*)(hT + (128 + kh) * 20 + i4) = h1;
      }
      __syncthreads();
      const int ks = tid >> 6, ml = (tid >> 2) & 15, b4 = tid & 3;
      float4 a0 = {0,0,0,0}, a1 = {0,0,0,0}, a2 = {0,0,0,0}, a3 = {0,0,0,0};
      {
        const float* xp = hT + (unsigned)(ks * 32) * 20 + b4 * 4;
        const float* wp = SLAB + (unsigned)(ks * 32) * 64 + ml * 4;
#pragma unroll 8
        for (int kk = 0; kk < 32; ++kk) {
          float4 xv = *(const float4*)(xp + kk * 20);
          float4 wv = *(const float4*)(wp + kk * 64);
          FMA16V(a0, a1, a2, a3, xv, wv);
        }
      }
      __syncthreads();
      {
        float* rp = red + (unsigned)(ks * 64 + ml * 4 + b4) * 20;
        *(float4*)(rp + 0) = a0; *(float4*)(rp + 4) = a1;
        *(float4*)(rp + 8) = a2; *(float4*)(rp + 12) = a3;
      }
      __syncthreads();
      float4 gate = {0,0,0,0};
      if (tid < 256) {
        int m2 = tid & 15, bl = tid >> 4;
        int t2 = m2 * 4 + (bl >> 2), bs = bl & 3;
#pragma unroll
        for (int k2 = 0; k2 < 8; ++k2) {
          float4 rr = *(const float4*)(red + (unsigned)(k2 * 64 + t2) * 20 + bs * 4);
          gate.x += rr.x; gate.y += rr.y; gate.z += rr.z; gate.w += rr.w;
        }
      }
      bar_wait(barp, barn);        // yt now visible
      if (tid < 256) {
        int m2 = tid & 15, bl = tid >> 4;
        float yt_reg = ld1s_sc1(ws + OFF_YT + b0 + bl);
        float gi = gate.x + yt_reg * wiD.x + bsD.x;
        float gf = gate.y + yt_reg * wiD.y + bsD.y;
        float gg = gate.z + yt_reg * wiD.z + bsD.z;
        float go = gate.w + yt_reg * wiD.w + bsD.w;
        float cn = fast_sig(gf) * cd_reg + fast_sig(gi) * fast_tanh(gg);
        float hn = fast_sig(go) * fast_tanh(cn);
        cd_reg = cn;
        unsigned m = mt * 16 + m2;
        st1_sc1(ws + OFF_HD + (unsigned)wr2 * 65536 + (unsigned)grp * 4096 + m * 16 + bl, hn);
        hcs[bl * 32 + m2] = hn;
        hcs[bl * 32 + 16 + m2] = cn;
      }
      __syncthreads();
      {  // Sd atomics: 8 batches per thread, j = tid&255
        int j = tid & 255, half = tid >> 8;
#pragma unroll
        for (int e2 = 0; e2 < 8; ++e2) {
          int bl2 = half * 8 + e2;
          const float* hp = hcs + bl2 * 32;
          float s = 0.f;
#pragma unroll
          for (int c = 0; c < 16; ++c) s += hp[c] * wreg[c];
#pragma unroll
          for (int c = 0; c < 16; ++c) s += hp[16 + c] * wreg[16 + c];
          atomic_add_sc1(ws + OFF_SDB + (unsigned)wr2 * 65536 + (unsigned)(b0 + bl2) * 256 + j, s);
        }
      }
    }
    barn += 16;
    bar_arrive(barp);            // drains h, Sd atomics
  }
  bar_wait(barp, barn);          // h_d, ctx published

  // ---------------- FINAL: hidden = [h_d, ctx] @ Wb_W.T + Wb_b; y = hidden @ vb_W.T + vb_b
  {
    float* hsf  = SCR;          // [16][516]
    float* hid2 = SCR + 8256;   // [2][16][17]
    {
      int l0 = tid * 2, l1 = tid * 2 + 1;
      int k0 = l0 >> 2, i0 = l0 & 3, k1 = l1 >> 2, i1 = l1 & 3;
      const float* hb = ws + OFF_HD + 65536u + (unsigned)grp * 4096;
      int bl0 = l0 >> 6, c0 = (l0 & 63) * 4, bl1 = l1 >> 6, c1 = (l1 & 63) * 4;
      float4 qa, qb, qc, qd;
      ld1q_nw(qa, hb + k0 * 16 + i0 * 4);
      ld1q_nw(qb, hb + k1 * 16 + i1 * 4);
      ld1q_nw(qc, ws + OFF_CTX + (unsigned)(b0 + bl0) * 256 + c0);
      ld1q_nw(qd, ws + OFF_CTX + (unsigned)(b0 + bl1) * 256 + c1);
      vm0();
      hsf[(i0 * 4 + 0) * 516 + k0] = qa.x; hsf[(i0 * 4 + 1) * 516 + k0] = qa.y;
      hsf[(i0 * 4 + 2) * 516 + k0] = qa.z; hsf[(i0 * 4 + 3) * 516 + k0] = qa.w;
      hsf[(i1 * 4 + 0) * 516 + k1] = qb.x; hsf[(i1 * 4 + 1) * 516 + k1] = qb.y;
      hsf[(i1 * 4 + 2) * 516 + k1] = qb.z; hsf[(i1 * 4 + 3) * 516 + k1] = qb.w;
      *(float4*)(hsf + bl0 * 516 + 256 + c0) = qc;
      *(float4*)(hsf + bl1 * 516 + 256 + c1) = qd;
    }
    __syncthreads();
    int bl = tid & 15, p4 = (tid >> 4) & 15, half = tid >> 8;
    int row = mt * 16 + p4;
    const float* wrow = WbW + (unsigned)row * 512 + half * 256;
    const float* hp = hsf + bl * 516 + half * 256;
    float acc = half ? 0.f : Wbb[row];
#pragma unroll 8
    for (int q = 0; q < 64; ++q)
      acc += dot4(*(const float4*)(hp + q * 4), *(const float4*)(wrow + q * 4));
    hid2[half * 272 + bl * 17 + p4] = acc;
    __syncthreads();
    if (tid < 16) {
      float s = 0.f;
#pragma unroll
      for (int p = 0; p < 16; ++p)
        s += (hid2[tid * 17 + p] + hid2[272 + tid * 17 + p]) * vbW[mt * 16 + p];
      if (mt == 0) s += vbb[0];
      atomicAdd(&out[b0 + tid], s);
    }
  }
}

extern "C" void kernel_launch(void* const* d_in, const int* in_sizes, int n_in,
                              void* d_out, int out_size, void* d_ws, size_t ws_size,
                              hipStream_t stream) {
  (void)in_sizes; (void)n_in; (void)out_size; (void)ws_size;
  const float* in    = (const float*)d_in[0];
  const float* WUe   = (const float*)d_in[1];
  const float* ve    = (const float*)d_in[2];
  const float* Wih_e = (const float*)d_in[3];
  const float* Whh_e = (const float*)d_in[4];
  const float* bih_e = (const float*)d_in[5];
  const float* bhh_e = (const float*)d_in[6];
  const float* WUd   = (const float*)d_in[7];
  const float* vd    = (const float*)d_in[8];
  const float* wbt   = (const float*)d_in[9];
  const float* Wih_d = (const float*)d_in[10];
  const float* Whh_d = (const float*)d_in[11];
  const float* bih_d = (const float*)d_in[12];
  const float* bhh_d = (const float*)d_in[13];
  const float* WbW   = (const float*)d_in[14];
  const float* Wbb   = (const float*)d_in[15];
  const float* vbW   = (const float*)d_in[16];
  const float* vbb   = (const float*)d_in[17];
  float* ws  = (float*)d_ws;
  float* out = (float*)d_out;

  (void)hipFuncSetAttribute((const void*)darnn_main,
                            hipFuncAttributeMaxDynamicSharedMemorySize, SMEM_BYTES);
  hipLaunchKernelGGL(darnn_init, dim3(1024), dim3(256), 0, stream, ws, out);
  hipLaunchKernelGGL(darnn_main, dim3(256), dim3(512), SMEM_BYTES, stream,
                     in, WUe, ve, Wih_e, Whh_e, bih_e, bhh_e,
                     WUd, vd, wbt, Wih_d, Whh_d, bih_d, bhh_d,
                     WbW, Wbb, vbW, vbb, ws, out);
}

// Round 8
// 1329.338 us; speedup vs baseline: 1.1471x; 1.0450x over previous
//
#include <hip/hip_runtime.h>
#include <math.h>

// Problem dims: B=256, T=64, N=128, M=256, P=256, YD=1
// 256 blocks x 512 threads. Group = 16 blocks = 16 batches; block role mt = m-tile.
// Wave specialization: waves 0-3 attention || waves 4-7 h-GEMM, per step.

// Workspace layout (float offsets)
#define OFF_XWT   0u
#define OFF_XEWT  2097152u
#define OFF_XE    6291456u
#define OFF_HE    10485760u   // [2][16][256][16] h_e transposed [buf][grp][k][bl]
#define OFF_HD    10616832u
#define OFF_SB    10747904u   // [2][256][64]
#define OFF_SDB   10780672u   // [2][256][256]
#define OFF_XA    10911744u   // [16][128][16]
#define OFF_CTX   10944512u
#define OFF_YT    11010048u
#define OFF_BAR   11010304u
#define WS_END    11010816u

// LDS: SLAB | PER | SCR | FLG
#define SLAB_F 24576
#define PER_F  2432
#define SCR_F  12288
#define FLG_F  16
#define SMEM_F (SLAB_F + PER_F + SCR_F + FLG_F)
#define SMEM_BYTES (SMEM_F * 4)   // 157248 <= 160 KB

#define F_E 0
#define F_L 1
#define F_B 2
#define F_Y 3

__device__ __forceinline__ float fast_tanh(float x) {
  float xc = fminf(15.f, fmaxf(-15.f, x));
  float e = __expf(2.f * xc);
  return 1.f - 2.f * __builtin_amdgcn_rcpf(e + 1.f);
}
__device__ __forceinline__ float fast_sig(float x) {
  float xc = fminf(30.f, fmaxf(-30.f, x));
  return __builtin_amdgcn_rcpf(1.f + __expf(-xc));
}
__device__ __forceinline__ float wave_max(float v) {
#pragma unroll
  for (int o = 32; o; o >>= 1) v = fmaxf(v, __shfl_xor(v, o));
  return v;
}
__device__ __forceinline__ float wave_sum(float v) {
#pragma unroll
  for (int o = 32; o; o >>= 1) v += __shfl_xor(v, o);
  return v;
}
__device__ __forceinline__ float dot4(float4 a, float4 b) {
  return a.x*b.x + a.y*b.y + a.z*b.z + a.w*b.w;
}

// ---- device-scope (sc1) helpers; float4 only as ASM OUTPUT ----
__device__ __forceinline__ void st1_sc1(float* p, float v) {
  asm volatile("global_store_dword %0, %1, off sc1" :: "v"(p), "v"(v) : "memory");
}
__device__ __forceinline__ void ld1q_sc1(float4& a, const float* pa) {
  asm volatile("global_load_dwordx4 %0, %1, off sc1\n\ts_waitcnt vmcnt(0)"
               : "=&v"(a) : "v"(pa) : "memory");
}
__device__ __forceinline__ void ld1q_nw(float4& a, const float* pa) {
  asm volatile("global_load_dwordx4 %0, %1, off sc1"
               : "=&v"(a) : "v"(pa) : "memory");
}
__device__ __forceinline__ void vm0() {
  asm volatile("s_waitcnt vmcnt(0)" ::: "memory");
}
__device__ __forceinline__ void lgk0() {
  asm volatile("s_waitcnt lgkmcnt(0)" ::: "memory");
}
__device__ __forceinline__ float ld1s_sc1(const float* p) {
  float v;
  asm volatile("global_load_dword %0, %1, off sc1\n\ts_waitcnt vmcnt(0)"
               : "=&v"(v) : "v"(p) : "memory");
  return v;
}
__device__ __forceinline__ void ld8s_sc1(
    float& a0,float& a1,float& a2,float& a3,float& a4,float& a5,float& a6,float& a7,
    const float* p0,const float* p1,const float* p2,const float* p3,
    const float* p4,const float* p5,const float* p6,const float* p7) {
  asm volatile(
      "global_load_dword %0, %8, off sc1\n\t"
      "global_load_dword %1, %9, off sc1\n\t"
      "global_load_dword %2, %10, off sc1\n\t"
      "global_load_dword %3, %11, off sc1\n\t"
      "global_load_dword %4, %12, off sc1\n\t"
      "global_load_dword %5, %13, off sc1\n\t"
      "global_load_dword %6, %14, off sc1\n\t"
      "global_load_dword %7, %15, off sc1\n\t"
      "s_waitcnt vmcnt(0)"
      : "=&v"(a0),"=&v"(a1),"=&v"(a2),"=&v"(a3),
        "=&v"(a4),"=&v"(a5),"=&v"(a6),"=&v"(a7)
      : "v"(p0),"v"(p1),"v"(p2),"v"(p3),"v"(p4),"v"(p5),"v"(p6),"v"(p7)
      : "memory");
}
__device__ __forceinline__ void atomic_add_sc1(float* p, float v) {
  asm volatile("global_atomic_add_f32 %0, %1, off sc1" :: "v"(p), "v"(v) : "memory");
}

// LDS flag sync (monotonic counters; subset-of-waves sync without s_barrier)
__device__ __forceinline__ void lds_inc(unsigned* f) {
  __hip_atomic_fetch_add(f, 1u, __ATOMIC_RELAXED, __HIP_MEMORY_SCOPE_WORKGROUP);
}
__device__ __forceinline__ void lds_poll(unsigned* f, unsigned tgt) {
  unsigned cur;
  do { cur = __hip_atomic_load(f, __ATOMIC_RELAXED, __HIP_MEMORY_SCOPE_WORKGROUP); } while (cur < tgt);
  asm volatile("" ::: "memory");
}

#define FMA16V(a0,a1,a2,a3,xv,wv) \
  a0.x += xv.x*wv.x; a0.y += xv.x*wv.y; a0.z += xv.x*wv.z; a0.w += xv.x*wv.w; \
  a1.x += xv.y*wv.x; a1.y += xv.y*wv.y; a1.z += xv.y*wv.z; a1.w += xv.y*wv.w; \
  a2.x += xv.z*wv.x; a2.y += xv.z*wv.y; a2.z += xv.z*wv.z; a2.w += xv.z*wv.w; \
  a3.x += xv.w*wv.x; a3.y += xv.w*wv.y; a3.z += xv.w*wv.z; a3.w += xv.w*wv.w;

// Split fence-free group barrier (monotonic counter, relaxed agent atomics)
__device__ __forceinline__ void bar_arrive(unsigned* bar) {
  asm volatile("s_waitcnt vmcnt(0)" ::: "memory");
  __syncthreads();
  if (threadIdx.x == 0)
    __hip_atomic_fetch_add(bar, 1u, __ATOMIC_RELAXED, __HIP_MEMORY_SCOPE_AGENT);
}
__device__ __forceinline__ void bar_wait(unsigned* bar, unsigned target) {
  if (threadIdx.x == 0) {
    unsigned cur;
    do {
      cur = __hip_atomic_load(bar, __ATOMIC_RELAXED, __HIP_MEMORY_SCOPE_AGENT);
    } while (cur < target);
  }
  __syncthreads();
}

__global__ void darnn_init(float* __restrict__ ws, float* __restrict__ out) {
  unsigned i = blockIdx.x * 256u + threadIdx.x;
  const unsigned span = WS_END - OFF_HE;
  for (unsigned idx = i; idx < span; idx += gridDim.x * 256u) ws[OFF_HE + idx] = 0.f;
  if (i < 256u) out[i] = 0.f;
}

__global__ __launch_bounds__(512, 2) void darnn_main(
    const float* __restrict__ in,   const float* __restrict__ WUe,   const float* __restrict__ ve,
    const float* __restrict__ Wih_e,const float* __restrict__ Whh_e,
    const float* __restrict__ bih_e,const float* __restrict__ bhh_e,
    const float* __restrict__ WUd,  const float* __restrict__ vd,
    const float* __restrict__ wbt,  const float* __restrict__ Wih_d,
    const float* __restrict__ Whh_d,const float* __restrict__ bih_d, const float* __restrict__ bhh_d,
    const float* __restrict__ WbW,  const float* __restrict__ Wbb,
    const float* __restrict__ vbW,  const float* __restrict__ vbb,
    float* __restrict__ ws, float* __restrict__ out)
{
  extern __shared__ __align__(16) float sm[];
  float* SLAB = sm;
  float* PER  = sm + SLAB_F;
  float* SCR  = sm + SLAB_F + PER_F;
  unsigned* FLG = (unsigned*)(sm + SLAB_F + PER_F + SCR_F);
  const int tid = threadIdx.x;
  const int bid = blockIdx.x;
  const int grp = bid >> 4;
  const int mt  = bid & 15;
  const int b0  = grp << 4;

  float* XWt  = ws + OFF_XWT;
  float* XeWt = ws + OFF_XEWT;
  float* Xe   = ws + OFF_XE;
  unsigned* barp = (unsigned*)(ws + OFF_BAR) + grp * 32;
  unsigned barn = 0;

  if (tid < FLG_F) FLG[tid] = 0u;

  // PER (encoder): wue_s [64][36]; ve_s @2304; bsum_e @2368
  float* wue_s  = PER;
  float* ve_s   = PER + 2304;
  float* bsum_e = PER + 2368;

  // ---- one-time encoder staging ----
  {
    int r = tid & 63, kq = tid >> 6;
    int grow = (r & 3) * 256 + mt * 16 + (r >> 2);
#pragma unroll 4
    for (int q = 0; q < 12; ++q) {
      int k = kq * 48 + q * 4;
      float4 wv = (k < 128) ? *(const float4*)(Wih_e + grow * 128 + k)
                            : *(const float4*)(Whh_e + grow * 256 + (k - 128));
      SLAB[(k + 0) * 64 + r] = wv.x; SLAB[(k + 1) * 64 + r] = wv.y;
      SLAB[(k + 2) * 64 + r] = wv.z; SLAB[(k + 3) * 64 + r] = wv.w;
    }
    {
      int lin = tid * 4;
      int j = lin >> 5, c0 = lin & 31;
      int col = (c0 < 16) ? (mt * 16 + c0) : (256 + mt * 16 + (c0 - 16));
      float4 wv = *(const float4*)(WUe + j * 576 + col);
      *(float4*)(wue_s + j * 36 + c0) = wv;
    }
    if (tid < 64) {
      ve_s[tid] = ve[tid];
      int g = tid >> 4, m2 = tid & 15, m = mt * 16 + m2;
      bsum_e[tid] = bih_e[g * 256 + m] + bhh_e[g * 256 + m];
    }
  }

  // ---------------- P1: XWt[bid][j][n] = sum_k X[bid][k][n] * WU_e[j][512+k]
  {
    float* Xs = SCR;  // [128][68]
    const float* Xb = in + bid * 8256;
    __syncthreads();
    for (int it = 0; it < 16; ++it) {
      int lin = tid + it * 512;
      int k = lin >> 7, n = lin & 127;
      Xs[n * 68 + k] = Xb[k * 129 + n];
    }
    __syncthreads();
    int j = tid & 63, nh = tid >> 6;
    float acc[16];
#pragma unroll
    for (int i = 0; i < 16; ++i) acc[i] = 0.f;
    const float* wrow = WUe + j * 576 + 512;
    for (int kc = 0; kc < 4; ++kc) {
      float4 w0 = *(const float4*)(wrow + kc * 16 + 0);
      float4 w1 = *(const float4*)(wrow + kc * 16 + 4);
      float4 w2 = *(const float4*)(wrow + kc * 16 + 8);
      float4 w3 = *(const float4*)(wrow + kc * 16 + 12);
#pragma unroll
      for (int ni = 0; ni < 16; ++ni) {
        const float* xp = Xs + (nh * 16 + ni) * 68 + kc * 16;
        acc[ni] += dot4(*(const float4*)(xp + 0),  w0) + dot4(*(const float4*)(xp + 4),  w1)
                 + dot4(*(const float4*)(xp + 8),  w2) + dot4(*(const float4*)(xp + 12), w3);
      }
    }
    float* dst = XWt + bid * 8192 + j * 128 + nh * 16;
#pragma unroll
    for (int ni = 0; ni < 16; ++ni) dst[ni] = acc[ni];
    __syncthreads();
  }

  // hoist regs (constant over t)
  float4 whc[8];
#pragma unroll
  for (int q = 0; q < 8; ++q) whc[q] = *(const float4*)(wue_s + (tid & 63) * 36 + q * 4);
  float4 bsE = {0,0,0,0};
  {
    int m2 = tid & 15;
    bsE.x = bsum_e[m2]; bsE.y = bsum_e[16 + m2];
    bsE.z = bsum_e[32 + m2]; bsE.w = bsum_e[48 + m2];
  }
  // xwreg: wave w (0-3), lane l: n in {l, l+64}, j in w*16..+15
  float xwreg[32];
  if (tid < 256) {
    int w = tid >> 6, l = tid & 63;
    const float* xwp = XWt + bid * 8192;
#pragma unroll
    for (int jj = 0; jj < 16; ++jj) {
      xwreg[jj]      = xwp[(w * 16 + jj) * 128 + l];
      xwreg[16 + jj] = xwp[(w * 16 + jj) * 128 + 64 + l];
    }
  }
  float c_reg = 0.f;

  // ================ ENCODER: 64 steps ================
  for (int t = 0; t < 64; ++t) {
    const int rd = t & 1, wr2 = (t + 1) & 1;
    float* xah = SCR + 1024;     // [384][20]
    const int ks = tid >> 6, ml = (tid >> 2) & 15, b4 = tid & 3;
    float4 a0 = {0,0,0,0}, a1 = {0,0,0,0}, a2 = {0,0,0,0}, a3 = {0,0,0,0};

    bar_wait(barp, barn);        // S(rd), h(rd) visible

    if (tid < 256) {
      // ---- attention (waves 0-3), arrives event B at the end (wave 0)
      int w = tid >> 6, l = tid & 63;
      float* Sj = SCR;           // [64]
      float* Ep = SCR + 64;      // [4][128]
      if (l < 16)
        Sj[w * 16 + l] = ld1s_sc1(ws + OFF_SB + (unsigned)rd * 16384 + (unsigned)bid * 64 + w * 16 + l);
      lgk0();
      float e0 = 0.f, e1 = 0.f;
#pragma unroll
      for (int jj = 0; jj < 16; ++jj) {
        float s = Sj[w * 16 + jj];
        float vv = ve_s[w * 16 + jj];
        e0 += vv * fast_tanh(xwreg[jj] + s);
        e1 += vv * fast_tanh(xwreg[16 + jj] + s);
      }
      Ep[w * 128 + l] = e0;
      Ep[w * 128 + 64 + l] = e1;
      lgk0();
      if (l == 0) lds_inc(FLG + F_E);
      if (w == 0) {
        lds_poll(FLG + F_E, 4u * (t + 1));
        float En0 = Ep[l] + Ep[128 + l] + Ep[256 + l] + Ep[384 + l];
        float En1 = Ep[64 + l] + Ep[192 + l] + Ep[320 + l] + Ep[448 + l];
        float mx = wave_max(fmaxf(En0, En1));
        float ex0 = __expf(En0 - mx), ex1 = __expf(En1 - mx);
        float tot = wave_sum(ex0 + ex1);
        float rt = __builtin_amdgcn_rcpf(tot);
        float x0 = in[bid * 8256 + t * 129 + l];
        float x1 = in[bid * 8256 + t * 129 + 64 + l];
        float* XAg = ws + OFF_XA + (unsigned)grp * 2048;
        st1_sc1(XAg + l * 16 + mt, x0 * ex0 * rt);
        st1_sc1(XAg + (64 + l) * 16 + mt, x1 * ex1 * rt);
        vm0();
        if (tid == 0)
          __hip_atomic_fetch_add(barp, 1u, __ATOMIC_RELAXED, __HIP_MEMORY_SCOPE_AGENT);
      }
    } else {
      // ---- h-part GEMM (waves 4-7): k in [128,384)
      int u = tid - 256;
      float4 h0, h1, h2, h3;
      const float* hb = ws + OFF_HE + (unsigned)rd * 65536 + (unsigned)grp * 4096 + u * 16;
      ld1q_nw(h0, hb); ld1q_nw(h1, hb + 4); ld1q_nw(h2, hb + 8); ld1q_nw(h3, hb + 12);
      vm0();
      float* row = xah + (unsigned)(128 + u) * 20;
      *(float4*)(row + 0) = h0; *(float4*)(row + 4) = h1;
      *(float4*)(row + 8) = h2; *(float4*)(row + 12) = h3;
      lgk0();
      int s = u >> 6;
      const float* xp = xah + (unsigned)(128 + s * 64) * 20 + b4 * 4;
      const float* wp = SLAB + (unsigned)(128 + s * 64) * 64 + ml * 4;
#pragma unroll 8
      for (int kk = 0; kk < 64; ++kk) {
        float4 xv = *(const float4*)(xp + kk * 20);
        float4 wv = *(const float4*)(wp + kk * 64);
        FMA16V(a0, a1, a2, a3, xv, wv);
      }
    }
    barn += 16;
    __syncthreads();             // rejoin all 8 waves
    bar_wait(barp, barn);        // all XAs visible

    if (tid < 16) {              // zero S[rd][bid] (own-batch buffer)
      float* sp = ws + OFF_SB + (unsigned)rd * 16384 + (unsigned)bid * 64 + tid * 4;
      st1_sc1(sp + 0, 0.f); st1_sc1(sp + 1, 0.f);
      st1_sc1(sp + 2, 0.f); st1_sc1(sp + 3, 0.f);
    }
    {  // stage XA rows 0..127
      int k = tid >> 2, i4 = (tid & 3) * 4;
      float4 q;
      ld1q_sc1(q, ws + OFF_XA + (unsigned)grp * 2048 + k * 16 + i4);
      *(float4*)(xah + k * 20 + i4) = q;
    }
    __syncthreads();
    {  // x-part: 8 strips x 16 k
      const float* xp = xah + (unsigned)(ks * 16) * 20 + b4 * 4;
      const float* wp = SLAB + (unsigned)(ks * 16) * 64 + ml * 4;
#pragma unroll 8
      for (int kk = 0; kk < 16; ++kk) {
        float4 xv = *(const float4*)(xp + kk * 20);
        float4 wv = *(const float4*)(wp + kk * 64);
        FMA16V(a0, a1, a2, a3, xv, wv);
      }
    }
    __syncthreads();             // xah dead -> red
    float* red = SCR;            // [512][20]
    {
      float* rp = red + (unsigned)(ks * 64 + ml * 4 + b4) * 20;
      *(float4*)(rp + 0) = a0; *(float4*)(rp + 4) = a1;
      *(float4*)(rp + 8) = a2; *(float4*)(rp + 12) = a3;
    }
    __syncthreads();
    float* hcs = SCR + 10240;    // [16][32]
    if (tid < 256) {
      int m2 = tid & 15, bl = tid >> 4;
      int t2 = m2 * 4 + (bl >> 2), bs = bl & 3;
      float4 gate = {0,0,0,0};
#pragma unroll
      for (int k2 = 0; k2 < 8; ++k2) {
        float4 rr = *(const float4*)(red + (unsigned)(k2 * 64 + t2) * 20 + bs * 4);
        gate.x += rr.x; gate.y += rr.y; gate.z += rr.z; gate.w += rr.w;
      }
      float gi = gate.x + bsE.x, gf = gate.y + bsE.y;
      float gg = gate.z + bsE.z, go = gate.w + bsE.w;
      float cn = fast_sig(gf) * c_reg + fast_sig(gi) * fast_tanh(gg);
      float hn = fast_sig(go) * fast_tanh(cn);
      c_reg = cn;
      unsigned m = mt * 16 + m2;
      st1_sc1(ws + OFF_HE + (unsigned)wr2 * 65536 + (unsigned)grp * 4096 + m * 16 + bl, hn);
      st1_sc1(Xe + ((unsigned)(b0 + bl) * 64 + t) * 256 + m, hn);
      hcs[bl * 32 + m2] = hn;
      hcs[bl * 32 + 16 + m2] = cn;
    }
    __syncthreads();
    {  // S atomics: 2 batches per thread
      int j = tid & 63, wq = tid >> 6;
#pragma unroll
      for (int e2 = 0; e2 < 2; ++e2) {
        int bl2 = wq * 2 + e2;
        const float* hp = hcs + bl2 * 32;
        float s = 0.f;
#pragma unroll
        for (int q = 0; q < 4; ++q) {
          s += dot4(*(const float4*)(hp + q * 4), whc[q]);
          s += dot4(*(const float4*)(hp + 16 + q * 4), whc[4 + q]);
        }
        atomic_add_sc1(ws + OFF_SB + (unsigned)wr2 * 16384 + (unsigned)(b0 + bl2) * 64 + j, s);
      }
    }
    barn += 16;
    bar_arrive(barp);
  }
  bar_wait(barp, barn);          // all Xe published

  // ---- fill Xe row into regs: tid<256, m = tid, all 64 t
  float xe[64];
  if (tid < 256) {
    const float* xb = Xe + (unsigned)bid * 16384 + tid;
#pragma unroll
    for (int g8 = 0; g8 < 8; ++g8) {
      ld8s_sc1(xe[g8*8+0], xe[g8*8+1], xe[g8*8+2], xe[g8*8+3],
               xe[g8*8+4], xe[g8*8+5], xe[g8*8+6], xe[g8*8+7],
               xb + (g8*8+0)*256, xb + (g8*8+1)*256, xb + (g8*8+2)*256,
               xb + (g8*8+3)*256, xb + (g8*8+4)*256, xb + (g8*8+5)*256,
               xb + (g8*8+6)*256, xb + (g8*8+7)*256);
    }
  }

  // ---- decoder one-time staging ----
  float* vd_s   = PER;
  float* wbt_s  = PER + 256;
  float* bsum_d = PER + 520;
  float* wihd_s = PER + 584;
  float* wudT   = SLAB + 16384;   // [32][256]
  __syncthreads();
  {
    int r = tid & 63, kq = tid >> 6;
    int grow = (r & 3) * 256 + mt * 16 + (r >> 2);
#pragma unroll 4
    for (int q = 0; q < 8; ++q) {
      int k = kq * 32 + q * 4;
      float4 wv = *(const float4*)(Whh_d + grow * 256 + k);
      SLAB[(k + 0) * 64 + r] = wv.x; SLAB[(k + 1) * 64 + r] = wv.y;
      SLAB[(k + 2) * 64 + r] = wv.z; SLAB[(k + 3) * 64 + r] = wv.w;
    }
    {
      int j = tid & 255, half = tid >> 8;
#pragma unroll
      for (int i = 0; i < 16; ++i) {
        int c = half * 16 + i;
        int col = (c < 16) ? (mt * 16 + c) : (256 + mt * 16 + (c - 16));
        wudT[c * 256 + j] = WUd[(unsigned)j * 768 + col];
      }
    }
    if (tid < 256) vd_s[tid] = vd[tid];
    if (tid < 257) wbt_s[tid] = wbt[tid];
    if (tid < 64) {
      int g = tid >> 4, m2 = tid & 15, m = mt * 16 + m2;
      bsum_d[tid] = bih_d[g * 256 + m] + bhh_d[g * 256 + m];
      wihd_s[tid] = Wih_d[g * 256 + m];
    }
  }
  __syncthreads();

  // ---------------- P2: XeWt[bid][j][t'] = sum_k Xe[bid][t'][k] * WU_d[j][512+k]
  {
    float* XeT = SCR;          // [64][64]
    float* Wdc = SCR + 4096;   // [64][128]
    int tt2 = tid & 15, jq = tid >> 4;
    for (int jc = 0; jc < 2; ++jc) {
      float4 c0 = {0,0,0,0}, c1 = {0,0,0,0}, c2 = {0,0,0,0}, c3 = {0,0,0,0};
      for (int kc = 0; kc < 4; ++kc) {
        __syncthreads();
        if (tid < 256 && (tid >> 6) == kc) {
          int kk = tid & 63;
#pragma unroll
          for (int t4 = 0; t4 < 16; ++t4) {
            float4 v = { xe[t4*4+0], xe[t4*4+1], xe[t4*4+2], xe[t4*4+3] };
            *(float4*)(XeT + kk * 64 + t4 * 4) = v;
          }
        }
        {
          int jj = tid >> 2, k16 = (tid & 3) * 16;
          const float* src = WUd + (unsigned)(jc * 128 + jj) * 768 + 512 + kc * 64 + k16;
#pragma unroll
          for (int s4 = 0; s4 < 4; ++s4) {
            float4 wv = *(const float4*)(src + s4 * 4);
            Wdc[(k16 + s4*4 + 0) * 128 + jj] = wv.x;
            Wdc[(k16 + s4*4 + 1) * 128 + jj] = wv.y;
            Wdc[(k16 + s4*4 + 2) * 128 + jj] = wv.z;
            Wdc[(k16 + s4*4 + 3) * 128 + jj] = wv.w;
          }
        }
        __syncthreads();
#pragma unroll 8
        for (int kk = 0; kk < 64; ++kk) {
          float4 xv = *(const float4*)(XeT + kk * 64 + tt2 * 4);
          float4 wv = *(const float4*)(Wdc + kk * 128 + jq * 4);
          FMA16V(c0, c1, c2, c3, wv, xv);
        }
      }
      int jb = jc * 128 + jq * 4;
      *(float4*)(XeWt + ((unsigned)bid * 256 + jb + 0) * 64 + tt2 * 4) = c0;
      *(float4*)(XeWt + ((unsigned)bid * 256 + jb + 1) * 64 + tt2 * 4) = c1;
      *(float4*)(XeWt + ((unsigned)bid * 256 + jb + 2) * 64 + tt2 * 4) = c2;
      *(float4*)(XeWt + ((unsigned)bid * 256 + jb + 3) * 64 + tt2 * 4) = c3;
    }
    __syncthreads();
  }

  // hoist decoder regs
  float wreg[32];
#pragma unroll
  for (int c = 0; c < 32; ++c) wreg[c] = wudT[c * 256 + (tid & 255)];
  float4 bsD = {0,0,0,0}, wiD = {0,0,0,0};
  {
    int m2 = tid & 15;
    bsD.x = bsum_d[m2]; bsD.y = bsum_d[16 + m2]; bsD.z = bsum_d[32 + m2]; bsD.w = bsum_d[48 + m2];
    wiD.x = wihd_s[m2]; wiD.y = wihd_s[16 + m2]; wiD.z = wihd_s[32 + m2]; wiD.w = wihd_s[48 + m2];
  }
  // xewreg: wave w (0-3), lane l = t': j in w*64..+63
  float xewreg[64];
  if (tid < 256) {
    int w = tid >> 6, l = tid & 63;
    const float* xew = XeWt + (unsigned)bid * 16384 + l;
#pragma unroll
    for (int jj = 0; jj < 64; ++jj) xewreg[jj] = xew[(w * 64 + jj) << 6];
  }
  float cd_reg = 0.f;

  // ================ DECODER: 63 steps ================
  for (int t = 0; t < 63; ++t) {
    const int rd = t & 1, wr2 = (t + 1) & 1;
    const int ml = (tid >> 2) & 15, b4 = tid & 3;
    float* hT  = SCR + 2048;     // [256][20]
    float* red = SCR + 7168;     // [256][20]

    bar_wait(barp, barn);        // Sd(rd), h(rd) visible

    if (tid < 256) {
      // ---- attention (waves 0-3), arrives event B (wave 0)
      int w = tid >> 6, l = tid & 63;
      float* Sdj  = SCR;         // [256]
      float* lp   = SCR + 256;   // [4][64]
      float* beta = SCR + 512;   // [64]
      float* r8   = SCR + 576;   // [8]
      Sdj[w * 64 + l] = ld1s_sc1(ws + OFF_SDB + (unsigned)rd * 65536 + (unsigned)bid * 256 + w * 64 + l);
      lgk0();
      float lpar = 0.f;
#pragma unroll 8
      for (int jj = 0; jj < 64; ++jj)
        lpar += vd_s[w * 64 + jj] * fast_tanh(xewreg[jj] + Sdj[w * 64 + jj]);
      lp[w * 64 + l] = lpar;
      lgk0();
      if (l == 0) lds_inc(FLG + F_L);
      if (w == 0) {
        lds_poll(FLG + F_L, 4u * (t + 1));
        float lv = lp[l] + lp[64 + l] + lp[128 + l] + lp[192 + l];
        float mx = wave_max(lv);
        float ex = __expf(lv - mx);
        float sw = wave_sum(ex);
        beta[l] = ex * __builtin_amdgcn_rcpf(sw);
        lgk0();
        if (l == 0) lds_inc(FLG + F_B);
      }
      lds_poll(FLG + F_B, (unsigned)(t + 1));
      lgk0();
      float ctx = 0.f;
#pragma unroll
      for (int tt = 0; tt < 64; ++tt) ctx += beta[tt] * xe[tt];
      st1_sc1(ws + OFF_CTX + (unsigned)bid * 256 + tid, ctx);
      float yp = ctx * wbt_s[1 + tid];
      float swv = wave_sum(yp);
      if (l == 0) r8[w] = swv;
      lgk0();
      if (l == 0) lds_inc(FLG + F_Y);
      if (w == 0) {
        lds_poll(FLG + F_Y, 4u * (t + 1));
        if (l == 0) {
          float yt = wbt_s[0] * in[bid * 8256 + t * 129 + 128] + r8[0] + r8[1] + r8[2] + r8[3];
          st1_sc1(ws + OFF_YT + bid, yt);
        }
        vm0();
        if (tid == 0)
          __hip_atomic_fetch_add(barp, 1u, __ATOMIC_RELAXED, __HIP_MEMORY_SCOPE_AGENT);
      }
    } else {
      // ---- full K=256 GEMM (waves 4-7) + red write
      int u = tid - 256;
      float4 h0, h1, h2, h3;
      const float* hb = ws + OFF_HD + (unsigned)rd * 65536 + (unsigned)grp * 4096 + u * 16;
      ld1q_nw(h0, hb); ld1q_nw(h1, hb + 4); ld1q_nw(h2, hb + 8); ld1q_nw(h3, hb + 12);
      vm0();
      float* row = hT + (unsigned)u * 20;
      *(float4*)(row + 0) = h0; *(float4*)(row + 4) = h1;
      *(float4*)(row + 8) = h2; *(float4*)(row + 12) = h3;
      lgk0();
      int s = u >> 6;
      float4 a0 = {0,0,0,0}, a1 = {0,0,0,0}, a2 = {0,0,0,0}, a3 = {0,0,0,0};
      const float* xp = hT + (unsigned)(s * 64) * 20 + b4 * 4;
      const float* wp = SLAB + (unsigned)(s * 64) * 64 + ml * 4;
#pragma unroll 8
      for (int kk = 0; kk < 64; ++kk) {
        float4 xv = *(const float4*)(xp + kk * 20);
        float4 wv = *(const float4*)(wp + kk * 64);
        FMA16V(a0, a1, a2, a3, xv, wv);
      }
      float* rp = red + (unsigned)(s * 64 + ml * 4 + b4) * 20;
      *(float4*)(rp + 0) = a0; *(float4*)(rp + 4) = a1;
      *(float4*)(rp + 8) = a2; *(float4*)(rp + 12) = a3;
    }
    barn += 16;
    __syncthreads();             // rejoin (red complete)

    float4 gate = {0,0,0,0};
    if (tid < 256) {
      int m2 = tid & 15, bl = tid >> 4;
      int t2 = m2 * 4 + (bl >> 2), bs = bl & 3;
#pragma unroll
      for (int k2 = 0; k2 < 4; ++k2) {
        float4 rr = *(const float4*)(red + (unsigned)(k2 * 64 + t2) * 20 + bs * 4);
        gate.x += rr.x; gate.y += rr.y; gate.z += rr.z; gate.w += rr.w;
      }
    }
    bar_wait(barp, barn);        // yt visible
    if (tid < 64) {              // zero Sd[rd][bid]
      float* sp = ws + OFF_SDB + (unsigned)rd * 65536 + (unsigned)bid * 256 + tid * 4;
      st1_sc1(sp + 0, 0.f); st1_sc1(sp + 1, 0.f);
      st1_sc1(sp + 2, 0.f); st1_sc1(sp + 3, 0.f);
    }
    float* hcs = SCR;            // [16][32] (attention scratch dead)
    if (tid < 256) {
      int m2 = tid & 15, bl = tid >> 4;
      float yt_reg = ld1s_sc1(ws + OFF_YT + b0 + bl);
      float gi = gate.x + yt_reg * wiD.x + bsD.x;
      float gf = gate.y + yt_reg * wiD.y + bsD.y;
      float gg = gate.z + yt_reg * wiD.z + bsD.z;
      float go = gate.w + yt_reg * wiD.w + bsD.w;
      float cn = fast_sig(gf) * cd_reg + fast_sig(gi) * fast_tanh(gg);
      float hn = fast_sig(go) * fast_tanh(cn);
      cd_reg = cn;
      unsigned m = mt * 16 + m2;
      st1_sc1(ws + OFF_HD + (unsigned)wr2 * 65536 + (unsigned)grp * 4096 + m * 16 + bl, hn);
      hcs[bl * 32 + m2] = hn;
      hcs[bl * 32 + 16 + m2] = cn;
    }
    __syncthreads();
    {  // Sd atomics: 8 batches per thread
      int j = tid & 255, half = tid >> 8;
#pragma unroll
      for (int e2 = 0; e2 < 8; ++e2) {
        int bl2 = half * 8 + e2;
        const float* hp = hcs + bl2 * 32;
        float s = 0.f;
#pragma unroll
        for (int c = 0; c < 16; ++c) s += hp[c] * wreg[c];
#pragma unroll
        for (int c = 0; c < 16; ++c) s += hp[16 + c] * wreg[16 + c];
        atomic_add_sc1(ws + OFF_SDB + (unsigned)wr2 * 65536 + (unsigned)(b0 + bl2) * 256 + j, s);
      }
    }
    barn += 16;
    bar_arrive(barp);
  }
  bar_wait(barp, barn);          // h_d, ctx published

  // ---------------- FINAL
  {
    float* hsf  = SCR;          // [16][516]
    float* hid2 = SCR + 8256;   // [2][16][17]
    {
      int l0 = tid * 2, l1 = tid * 2 + 1;
      int k0 = l0 >> 2, i0 = l0 & 3, k1 = l1 >> 2, i1 = l1 & 3;
      const float* hb = ws + OFF_HD + 65536u + (unsigned)grp * 4096;
      int bl0 = l0 >> 6, c0 = (l0 & 63) * 4, bl1 = l1 >> 6, c1 = (l1 & 63) * 4;
      float4 qa, qb, qc, qd;
      ld1q_nw(qa, hb + k0 * 16 + i0 * 4);
      ld1q_nw(qb, hb + k1 * 16 + i1 * 4);
      ld1q_nw(qc, ws + OFF_CTX + (unsigned)(b0 + bl0) * 256 + c0);
      ld1q_nw(qd, ws + OFF_CTX + (unsigned)(b0 + bl1) * 256 + c1);
      vm0();
      hsf[(i0 * 4 + 0) * 516 + k0] = qa.x; hsf[(i0 * 4 + 1) * 516 + k0] = qa.y;
      hsf[(i0 * 4 + 2) * 516 + k0] = qa.z; hsf[(i0 * 4 + 3) * 516 + k0] = qa.w;
      hsf[(i1 * 4 + 0) * 516 + k1] = qb.x; hsf[(i1 * 4 + 1) * 516 + k1] = qb.y;
      hsf[(i1 * 4 + 2) * 516 + k1] = qb.z; hsf[(i1 * 4 + 3) * 516 + k1] = qb.w;
      *(float4*)(hsf + bl0 * 516 + 256 + c0) = qc;
      *(float4*)(hsf + bl1 * 516 + 256 + c1) = qd;
    }
    __syncthreads();
    int bl = tid & 15, p4 = (tid >> 4) & 15, half = tid >> 8;
    int row = mt * 16 + p4;
    const float* wrow = WbW + (unsigned)row * 512 + half * 256;
    const float* hp = hsf + bl * 516 + half * 256;
    float acc = half ? 0.f : Wbb[row];
#pragma unroll 8
    for (int q = 0; q < 64; ++q)
      acc += dot4(*(const float4*)(hp + q * 4), *(const float4*)(wrow + q * 4));
    hid2[half * 272 + bl * 17 + p4] = acc;
    __syncthreads();
    if (tid < 16) {
      float s = 0.f;
#pragma unroll
      for (int p = 0; p < 16; ++p)
        s += (hid2[tid * 17 + p] + hid2[272 + tid * 17 + p]) * vbW[mt * 16 + p];
      if (mt == 0) s += vbb[0];
      atomicAdd(&out[b0 + tid], s);
    }
  }
}

extern "C" void kernel_launch(void* const* d_in, const int* in_sizes, int n_in,
                              void* d_out, int out_size, void* d_ws, size_t ws_size,
                              hipStream_t stream) {
  (void)in_sizes; (void)n_in; (void)out_size; (void)ws_size;
  const float* in    = (const float*)d_in[0];
  const float* WUe   = (const float*)d_in[1];
  const float* ve    = (const float*)d_in[2];
  const float* Wih_e = (const float*)d_in[3];
  const float* Whh_e = (const float*)d_in[4];
  const float* bih_e = (const float*)d_in[5];
  const float* bhh_e = (const float*)d_in[6];
  const float* WUd   = (const float*)d_in[7];
  const float* vd    = (const float*)d_in[8];
  const float* wbt   = (const float*)d_in[9];
  const float* Wih_d = (const float*)d_in[10];
  const float* Whh_d = (const float*)d_in[11];
  const float* bih_d = (const float*)d_in[12];
  const float* bhh_d = (const float*)d_in[13];
  const float* WbW   = (const float*)d_in[14];
  const float* Wbb   = (const float*)d_in[15];
  const float* vbW   = (const float*)d_in[16];
  const float* vbb   = (const float*)d_in[17];
  float* ws  = (float*)d_ws;
  float* out = (float*)d_out;

  (void)hipFuncSetAttribute((const void*)darnn_main,
                            hipFuncAttributeMaxDynamicSharedMemorySize, SMEM_BYTES);
  hipLaunchKernelGGL(darnn_init, dim3(1024), dim3(256), 0, stream, ws, out);
  hipLaunchKernelGGL(darnn_main, dim3(256), dim3(512), SMEM_BYTES, stream,
                     in, WUe, ve, Wih_e, Whh_e, bih_e, bhh_e,
                     WUd, vd, wbt, Wih_d, Whh_d, bih_d, bhh_d,
                     WbW, Wbb, vbW, vbb, ws, out);
}

// Round 9
// 1324.428 us; speedup vs baseline: 1.1514x; 1.0037x over previous
//
#include <hip/hip_runtime.h>
#include <math.h>

// Problem dims: B=256, T=64, N=128, M=256, P=256, YD=1
// 256 blocks x 512 threads. Group = 16 blocks = 16 batches; block role mt = m-tile.
// Wave specialization: waves 0-3 attention || waves 4-7 h-GEMM, per step.

// Workspace layout (float offsets)
#define OFF_XWT   0u
#define OFF_XEWT  2097152u
#define OFF_XE    6291456u
#define OFF_HE    10485760u   // [2][16][256][16] h_e transposed [buf][grp][k][bl]
#define OFF_HD    10616832u
#define OFF_SB    10747904u   // [2][256][64]
#define OFF_SDB   10780672u   // [2][256][256]
#define OFF_XA    10911744u   // [16][128][16]
#define OFF_CTX   10944512u
#define OFF_YT    11010048u
#define OFF_BAR   11010304u
#define WS_END    11010816u

// LDS: SLAB | PER | SCR | FLG
#define SLAB_F 24576
#define PER_F  2432
#define SCR_F  12288
#define FLG_F  16
#define SMEM_F (SLAB_F + PER_F + SCR_F + FLG_F)
#define SMEM_BYTES (SMEM_F * 4)   // 157248 <= 160 KB

#define F_E 0
#define F_L 1
#define F_B 2
#define F_Y 3

__device__ __forceinline__ float fast_tanh(float x) {
  float xc = fminf(15.f, fmaxf(-15.f, x));
  float e = __expf(2.f * xc);
  return 1.f - 2.f * __builtin_amdgcn_rcpf(e + 1.f);
}
__device__ __forceinline__ float fast_sig(float x) {
  float xc = fminf(30.f, fmaxf(-30.f, x));
  return __builtin_amdgcn_rcpf(1.f + __expf(-xc));
}
__device__ __forceinline__ float wave_max(float v) {
#pragma unroll
  for (int o = 32; o; o >>= 1) v = fmaxf(v, __shfl_xor(v, o));
  return v;
}
__device__ __forceinline__ float wave_sum(float v) {
#pragma unroll
  for (int o = 32; o; o >>= 1) v += __shfl_xor(v, o);
  return v;
}
__device__ __forceinline__ float dot4(float4 a, float4 b) {
  return a.x*b.x + a.y*b.y + a.z*b.z + a.w*b.w;
}

// ---- device-scope (sc1) helpers; float4 only as ASM OUTPUT ----
__device__ __forceinline__ void st1_sc1(float* p, float v) {
  asm volatile("global_store_dword %0, %1, off sc1" :: "v"(p), "v"(v) : "memory");
}
__device__ __forceinline__ void ld1q_sc1(float4& a, const float* pa) {
  asm volatile("global_load_dwordx4 %0, %1, off sc1\n\ts_waitcnt vmcnt(0)"
               : "=&v"(a) : "v"(pa) : "memory");
}
__device__ __forceinline__ void ld1q_nw(float4& a, const float* pa) {
  asm volatile("global_load_dwordx4 %0, %1, off sc1"
               : "=&v"(a) : "v"(pa) : "memory");
}
__device__ __forceinline__ void vm0() {
  asm volatile("s_waitcnt vmcnt(0)" ::: "memory");
}
__device__ __forceinline__ void lgk0() {
  asm volatile("s_waitcnt lgkmcnt(0)" ::: "memory");
}
__device__ __forceinline__ float ld1s_sc1(const float* p) {
  float v;
  asm volatile("global_load_dword %0, %1, off sc1\n\ts_waitcnt vmcnt(0)"
               : "=&v"(v) : "v"(p) : "memory");
  return v;
}
__device__ __forceinline__ void ld8s_sc1(
    float& a0,float& a1,float& a2,float& a3,float& a4,float& a5,float& a6,float& a7,
    const float* p0,const float* p1,const float* p2,const float* p3,
    const float* p4,const float* p5,const float* p6,const float* p7) {
  asm volatile(
      "global_load_dword %0, %8, off sc1\n\t"
      "global_load_dword %1, %9, off sc1\n\t"
      "global_load_dword %2, %10, off sc1\n\t"
      "global_load_dword %3, %11, off sc1\n\t"
      "global_load_dword %4, %12, off sc1\n\t"
      "global_load_dword %5, %13, off sc1\n\t"
      "global_load_dword %6, %14, off sc1\n\t"
      "global_load_dword %7, %15, off sc1\n\t"
      "s_waitcnt vmcnt(0)"
      : "=&v"(a0),"=&v"(a1),"=&v"(a2),"=&v"(a3),
        "=&v"(a4),"=&v"(a5),"=&v"(a6),"=&v"(a7)
      : "v"(p0),"v"(p1),"v"(p2),"v"(p3),"v"(p4),"v"(p5),"v"(p6),"v"(p7)
      : "memory");
}
__device__ __forceinline__ void atomic_add_sc1(float* p, float v) {
  asm volatile("global_atomic_add_f32 %0, %1, off sc1" :: "v"(p), "v"(v) : "memory");
}

// LDS flag sync (monotonic counters; subset-of-waves sync without s_barrier)
__device__ __forceinline__ void lds_inc(unsigned* f) {
  __hip_atomic_fetch_add(f, 1u, __ATOMIC_RELAXED, __HIP_MEMORY_SCOPE_WORKGROUP);
}
__device__ __forceinline__ void lds_poll(unsigned* f, unsigned tgt) {
  unsigned cur;
  do { cur = __hip_atomic_load(f, __ATOMIC_RELAXED, __HIP_MEMORY_SCOPE_WORKGROUP); } while (cur < tgt);
  asm volatile("" ::: "memory");
}

#define FMA16V(a0,a1,a2,a3,xv,wv) \
  a0.x += xv.x*wv.x; a0.y += xv.x*wv.y; a0.z += xv.x*wv.z; a0.w += xv.x*wv.w; \
  a1.x += xv.y*wv.x; a1.y += xv.y*wv.y; a1.z += xv.y*wv.z; a1.w += xv.y*wv.w; \
  a2.x += xv.z*wv.x; a2.y += xv.z*wv.y; a2.z += xv.z*wv.z; a2.w += xv.z*wv.w; \
  a3.x += xv.w*wv.x; a3.y += xv.w*wv.y; a3.z += xv.w*wv.z; a3.w += xv.w*wv.w;

// Split fence-free group barrier (monotonic counter, relaxed agent atomics)
__device__ __forceinline__ void bar_arrive(unsigned* bar) {
  asm volatile("s_waitcnt vmcnt(0)" ::: "memory");
  __syncthreads();
  if (threadIdx.x == 0)
    __hip_atomic_fetch_add(bar, 1u, __ATOMIC_RELAXED, __HIP_MEMORY_SCOPE_AGENT);
}
__device__ __forceinline__ void bar_wait(unsigned* bar, unsigned target) {
  if (threadIdx.x == 0) {
    unsigned cur;
    do {
      __builtin_amdgcn_s_sleep(1);   // backoff: avoid IC poll livelock (R8 outlier)
      cur = __hip_atomic_load(bar, __ATOMIC_RELAXED, __HIP_MEMORY_SCOPE_AGENT);
    } while (cur < target);
  }
  __syncthreads();
}

__global__ void darnn_init(float* __restrict__ ws, float* __restrict__ out) {
  unsigned i = blockIdx.x * 256u + threadIdx.x;
  const unsigned span = WS_END - OFF_HE;
  for (unsigned idx = i; idx < span; idx += gridDim.x * 256u) ws[OFF_HE + idx] = 0.f;
  if (i < 256u) out[i] = 0.f;
}

__global__ __launch_bounds__(512, 2) void darnn_main(
    const float* __restrict__ in,   const float* __restrict__ WUe,   const float* __restrict__ ve,
    const float* __restrict__ Wih_e,const float* __restrict__ Whh_e,
    const float* __restrict__ bih_e,const float* __restrict__ bhh_e,
    const float* __restrict__ WUd,  const float* __restrict__ vd,
    const float* __restrict__ wbt,  const float* __restrict__ Wih_d,
    const float* __restrict__ Whh_d,const float* __restrict__ bih_d, const float* __restrict__ bhh_d,
    const float* __restrict__ WbW,  const float* __restrict__ Wbb,
    const float* __restrict__ vbW,  const float* __restrict__ vbb,
    float* __restrict__ ws, float* __restrict__ out)
{
  extern __shared__ __align__(16) float sm[];
  float* SLAB = sm;
  float* PER  = sm + SLAB_F;
  float* SCR  = sm + SLAB_F + PER_F;
  unsigned* FLG = (unsigned*)(sm + SLAB_F + PER_F + SCR_F);
  const int tid = threadIdx.x;
  const int bid = blockIdx.x;
  const int grp = bid >> 4;
  const int mt  = bid & 15;
  const int b0  = grp << 4;

  float* XWt  = ws + OFF_XWT;
  float* XeWt = ws + OFF_XEWT;
  float* Xe   = ws + OFF_XE;
  unsigned* barp = (unsigned*)(ws + OFF_BAR) + grp * 32;
  unsigned barn = 0;

  if (tid < FLG_F) FLG[tid] = 0u;

  // PER (encoder): wue_s [64][36]; ve_s @2304; bsum_e @2368
  float* wue_s  = PER;
  float* ve_s   = PER + 2304;
  float* bsum_e = PER + 2368;

  // rotated S-row for this thread's atomic sweep (de-conflicts cross-block RMW)
  const int jfixE = ((tid & 63) + mt * 4) & 63;

  // ---- one-time encoder staging ----
  {
    int r = tid & 63, kq = tid >> 6;
    int grow = (r & 3) * 256 + mt * 16 + (r >> 2);
#pragma unroll 4
    for (int q = 0; q < 12; ++q) {
      int k = kq * 48 + q * 4;
      float4 wv = (k < 128) ? *(const float4*)(Wih_e + grow * 128 + k)
                            : *(const float4*)(Whh_e + grow * 256 + (k - 128));
      SLAB[(k + 0) * 64 + r] = wv.x; SLAB[(k + 1) * 64 + r] = wv.y;
      SLAB[(k + 2) * 64 + r] = wv.z; SLAB[(k + 3) * 64 + r] = wv.w;
    }
    {
      int lin = tid * 4;
      int j = lin >> 5, c0 = lin & 31;
      int col = (c0 < 16) ? (mt * 16 + c0) : (256 + mt * 16 + (c0 - 16));
      float4 wv = *(const float4*)(WUe + j * 576 + col);
      *(float4*)(wue_s + j * 36 + c0) = wv;
    }
    if (tid < 64) {
      ve_s[tid] = ve[tid];
      int g = tid >> 4, m2 = tid & 15, m = mt * 16 + m2;
      bsum_e[tid] = bih_e[g * 256 + m] + bhh_e[g * 256 + m];
    }
  }

  // ---------------- P1: XWt[bid][j][n] = sum_k X[bid][k][n] * WU_e[j][512+k]
  {
    float* Xs = SCR;  // [128][68]
    const float* Xb = in + bid * 8256;
    __syncthreads();
    for (int it = 0; it < 16; ++it) {
      int lin = tid + it * 512;
      int k = lin >> 7, n = lin & 127;
      Xs[n * 68 + k] = Xb[k * 129 + n];
    }
    __syncthreads();
    int j = tid & 63, nh = tid >> 6;
    float acc[16];
#pragma unroll
    for (int i = 0; i < 16; ++i) acc[i] = 0.f;
    const float* wrow = WUe + j * 576 + 512;
    for (int kc = 0; kc < 4; ++kc) {
      float4 w0 = *(const float4*)(wrow + kc * 16 + 0);
      float4 w1 = *(const float4*)(wrow + kc * 16 + 4);
      float4 w2 = *(const float4*)(wrow + kc * 16 + 8);
      float4 w3 = *(const float4*)(wrow + kc * 16 + 12);
#pragma unroll
      for (int ni = 0; ni < 16; ++ni) {
        const float* xp = Xs + (nh * 16 + ni) * 68 + kc * 16;
        acc[ni] += dot4(*(const float4*)(xp + 0),  w0) + dot4(*(const float4*)(xp + 4),  w1)
                 + dot4(*(const float4*)(xp + 8),  w2) + dot4(*(const float4*)(xp + 12), w3);
      }
    }
    float* dst = XWt + bid * 8192 + j * 128 + nh * 16;
#pragma unroll
    for (int ni = 0; ni < 16; ++ni) dst[ni] = acc[ni];
    __syncthreads();
  }

  // hoist regs (constant over t); whc holds weights for ROTATED row jfixE
  float4 whc[8];
#pragma unroll
  for (int q = 0; q < 8; ++q) whc[q] = *(const float4*)(wue_s + jfixE * 36 + q * 4);
  float4 bsE = {0,0,0,0};
  {
    int m2 = tid & 15;
    bsE.x = bsum_e[m2]; bsE.y = bsum_e[16 + m2];
    bsE.z = bsum_e[32 + m2]; bsE.w = bsum_e[48 + m2];
  }
  // xwreg: wave w (0-3), lane l: n in {l, l+64}, j in w*16..+15
  float xwreg[32];
  if (tid < 256) {
    int w = tid >> 6, l = tid & 63;
    const float* xwp = XWt + bid * 8192;
#pragma unroll
    for (int jj = 0; jj < 16; ++jj) {
      xwreg[jj]      = xwp[(w * 16 + jj) * 128 + l];
      xwreg[16 + jj] = xwp[(w * 16 + jj) * 128 + 64 + l];
    }
  }
  float c_reg = 0.f;

  // ================ ENCODER: 64 steps ================
  for (int t = 0; t < 64; ++t) {
    const int rd = t & 1, wr2 = (t + 1) & 1;
    float* xah = SCR + 1024;     // [384][20]
    const int ks = tid >> 6, ml = (tid >> 2) & 15, b4 = tid & 3;
    float4 a0 = {0,0,0,0}, a1 = {0,0,0,0}, a2 = {0,0,0,0}, a3 = {0,0,0,0};

    bar_wait(barp, barn);        // S(rd), h(rd) visible

    if (tid < 256) {
      // ---- attention (waves 0-3), arrives event B at the end (wave 0)
      int w = tid >> 6, l = tid & 63;
      float* Sj = SCR;           // [64]
      float* Ep = SCR + 64;      // [4][128]
      if (l < 16)
        Sj[w * 16 + l] = ld1s_sc1(ws + OFF_SB + (unsigned)rd * 16384 + (unsigned)bid * 64 + w * 16 + l);
      lgk0();
      float e0 = 0.f, e1 = 0.f;
#pragma unroll
      for (int jj = 0; jj < 16; ++jj) {
        float s = Sj[w * 16 + jj];
        float vv = ve_s[w * 16 + jj];
        e0 += vv * fast_tanh(xwreg[jj] + s);
        e1 += vv * fast_tanh(xwreg[16 + jj] + s);
      }
      Ep[w * 128 + l] = e0;
      Ep[w * 128 + 64 + l] = e1;
      lgk0();
      if (l == 0) lds_inc(FLG + F_E);
      if (w == 0) {
        lds_poll(FLG + F_E, 4u * (t + 1));
        float En0 = Ep[l] + Ep[128 + l] + Ep[256 + l] + Ep[384 + l];
        float En1 = Ep[64 + l] + Ep[192 + l] + Ep[320 + l] + Ep[448 + l];
        float mx = wave_max(fmaxf(En0, En1));
        float ex0 = __expf(En0 - mx), ex1 = __expf(En1 - mx);
        float tot = wave_sum(ex0 + ex1);
        float rt = __builtin_amdgcn_rcpf(tot);
        float x0 = in[bid * 8256 + t * 129 + l];
        float x1 = in[bid * 8256 + t * 129 + 64 + l];
        float* XAg = ws + OFF_XA + (unsigned)grp * 2048;
        st1_sc1(XAg + l * 16 + mt, x0 * ex0 * rt);
        st1_sc1(XAg + (64 + l) * 16 + mt, x1 * ex1 * rt);
        vm0();
        if (tid == 0)
          __hip_atomic_fetch_add(barp, 1u, __ATOMIC_RELAXED, __HIP_MEMORY_SCOPE_AGENT);
      }
    } else {
      // ---- h-part GEMM (waves 4-7): k in [128,384)
      int u = tid - 256;
      float4 h0, h1, h2, h3;
      const float* hb = ws + OFF_HE + (unsigned)rd * 65536 + (unsigned)grp * 4096 + u * 16;
      ld1q_nw(h0, hb); ld1q_nw(h1, hb + 4); ld1q_nw(h2, hb + 8); ld1q_nw(h3, hb + 12);
      vm0();
      float* row = xah + (unsigned)(128 + u) * 20;
      *(float4*)(row + 0) = h0; *(float4*)(row + 4) = h1;
      *(float4*)(row + 8) = h2; *(float4*)(row + 12) = h3;
      lgk0();
      int s = u >> 6;
      const float* xp = xah + (unsigned)(128 + s * 64) * 20 + b4 * 4;
      const float* wp = SLAB + (unsigned)(128 + s * 64) * 64 + ml * 4;
#pragma unroll 8
      for (int kk = 0; kk < 64; ++kk) {
        float4 xv = *(const float4*)(xp + kk * 20);
        float4 wv = *(const float4*)(wp + kk * 64);
        FMA16V(a0, a1, a2, a3, xv, wv);
      }
    }
    barn += 16;
    bar_wait(barp, barn);        // all XAs visible (internal sync rejoins waves)

    if (tid < 16) {              // zero S[rd][bid] (own-batch buffer)
      float* sp = ws + OFF_SB + (unsigned)rd * 16384 + (unsigned)bid * 64 + tid * 4;
      st1_sc1(sp + 0, 0.f); st1_sc1(sp + 1, 0.f);
      st1_sc1(sp + 2, 0.f); st1_sc1(sp + 3, 0.f);
    }
    {  // per-wave XA staging: wave ks stages exactly rows ks*16..+15 it consumes
      int l = tid & 63;
      int k = (ks << 4) + (l >> 2), i4 = (l & 3) * 4;
      float4 q;
      ld1q_sc1(q, ws + OFF_XA + (unsigned)grp * 2048 + k * 16 + i4);
      *(float4*)(xah + k * 20 + i4) = q;
      lgk0();                    // wave-local: no block sync needed
    }
    {  // x-part: 8 strips x 16 k
      const float* xp = xah + (unsigned)(ks * 16) * 20 + b4 * 4;
      const float* wp = SLAB + (unsigned)(ks * 16) * 64 + ml * 4;
#pragma unroll 8
      for (int kk = 0; kk < 16; ++kk) {
        float4 xv = *(const float4*)(xp + kk * 20);
        float4 wv = *(const float4*)(wp + kk * 64);
        FMA16V(a0, a1, a2, a3, xv, wv);
      }
    }
    __syncthreads();             // xah dead -> red
    float* red = SCR;            // [512][20]
    {
      float* rp = red + (unsigned)(ks * 64 + ml * 4 + b4) * 20;
      *(float4*)(rp + 0) = a0; *(float4*)(rp + 4) = a1;
      *(float4*)(rp + 8) = a2; *(float4*)(rp + 12) = a3;
    }
    __syncthreads();
    float* hcs = SCR + 10240;    // [16][32]
    if (tid < 256) {
      int m2 = tid & 15, bl = tid >> 4;
      int t2 = m2 * 4 + (bl >> 2), bs = bl & 3;
      float4 gate = {0,0,0,0};
#pragma unroll
      for (int k2 = 0; k2 < 8; ++k2) {
        float4 rr = *(const float4*)(red + (unsigned)(k2 * 64 + t2) * 20 + bs * 4);
        gate.x += rr.x; gate.y += rr.y; gate.z += rr.z; gate.w += rr.w;
      }
      float gi = gate.x + bsE.x, gf = gate.y + bsE.y;
      float gg = gate.z + bsE.z, go = gate.w + bsE.w;
      float cn = fast_sig(gf) * c_reg + fast_sig(gi) * fast_tanh(gg);
      float hn = fast_sig(go) * fast_tanh(cn);
      c_reg = cn;
      unsigned m = mt * 16 + m2;
      st1_sc1(ws + OFF_HE + (unsigned)wr2 * 65536 + (unsigned)grp * 4096 + m * 16 + bl, hn);
      st1_sc1(Xe + ((unsigned)(b0 + bl) * 64 + t) * 256 + m, hn);
      hcs[bl * 32 + m2] = hn;
      hcs[bl * 32 + 16 + m2] = cn;
    }
    __syncthreads();
    {  // S atomics: 2 batches per thread, ROTATED row jfixE (de-conflicted)
      int wq = tid >> 6;
#pragma unroll
      for (int e2 = 0; e2 < 2; ++e2) {
        int bl2 = wq * 2 + e2;
        const float* hp = hcs + bl2 * 32;
        float s = 0.f;
#pragma unroll
        for (int q = 0; q < 4; ++q) {
          s += dot4(*(const float4*)(hp + q * 4), whc[q]);
          s += dot4(*(const float4*)(hp + 16 + q * 4), whc[4 + q]);
        }
        atomic_add_sc1(ws + OFF_SB + (unsigned)wr2 * 16384 + (unsigned)(b0 + bl2) * 64 + jfixE, s);
      }
    }
    barn += 16;
    bar_arrive(barp);
  }
  bar_wait(barp, barn);          // all Xe published

  // ---- fill Xe row into regs: tid<256, m = tid, all 64 t
  float xe[64];
  if (tid < 256) {
    const float* xb = Xe + (unsigned)bid * 16384 + tid;
#pragma unroll
    for (int g8 = 0; g8 < 8; ++g8) {
      ld8s_sc1(xe[g8*8+0], xe[g8*8+1], xe[g8*8+2], xe[g8*8+3],
               xe[g8*8+4], xe[g8*8+5], xe[g8*8+6], xe[g8*8+7],
               xb + (g8*8+0)*256, xb + (g8*8+1)*256, xb + (g8*8+2)*256,
               xb + (g8*8+3)*256, xb + (g8*8+4)*256, xb + (g8*8+5)*256,
               xb + (g8*8+6)*256, xb + (g8*8+7)*256);
    }
  }

  // ---- decoder one-time staging ----
  float* vd_s   = PER;
  float* wbt_s  = PER + 256;
  float* bsum_d = PER + 520;
  float* wihd_s = PER + 584;
  float* wudT   = SLAB + 16384;   // [32][256]
  const int jfixD = ((tid & 255) + mt * 16) & 255;
  __syncthreads();
  {
    int r = tid & 63, kq = tid >> 6;
    int grow = (r & 3) * 256 + mt * 16 + (r >> 2);
#pragma unroll 4
    for (int q = 0; q < 8; ++q) {
      int k = kq * 32 + q * 4;
      float4 wv = *(const float4*)(Whh_d + grow * 256 + k);
      SLAB[(k + 0) * 64 + r] = wv.x; SLAB[(k + 1) * 64 + r] = wv.y;
      SLAB[(k + 2) * 64 + r] = wv.z; SLAB[(k + 3) * 64 + r] = wv.w;
    }
    {
      int j = tid & 255, half = tid >> 8;
#pragma unroll
      for (int i = 0; i < 16; ++i) {
        int c = half * 16 + i;
        int col = (c < 16) ? (mt * 16 + c) : (256 + mt * 16 + (c - 16));
        wudT[c * 256 + j] = WUd[(unsigned)j * 768 + col];
      }
    }
    if (tid < 256) vd_s[tid] = vd[tid];
    if (tid < 257) wbt_s[tid] = wbt[tid];
    if (tid < 64) {
      int g = tid >> 4, m2 = tid & 15, m = mt * 16 + m2;
      bsum_d[tid] = bih_d[g * 256 + m] + bhh_d[g * 256 + m];
      wihd_s[tid] = Wih_d[g * 256 + m];
    }
  }
  __syncthreads();

  // ---------------- P2: XeWt[bid][j][t'] = sum_k Xe[bid][t'][k] * WU_d[j][512+k]
  {
    float* XeT = SCR;          // [64][64]
    float* Wdc = SCR + 4096;   // [64][128]
    int tt2 = tid & 15, jq = tid >> 4;
    for (int jc = 0; jc < 2; ++jc) {
      float4 c0 = {0,0,0,0}, c1 = {0,0,0,0}, c2 = {0,0,0,0}, c3 = {0,0,0,0};
      for (int kc = 0; kc < 4; ++kc) {
        __syncthreads();
        if (tid < 256 && (tid >> 6) == kc) {
          int kk = tid & 63;
#pragma unroll
          for (int t4 = 0; t4 < 16; ++t4) {
            float4 v = { xe[t4*4+0], xe[t4*4+1], xe[t4*4+2], xe[t4*4+3] };
            *(float4*)(XeT + kk * 64 + t4 * 4) = v;
          }
        }
        {
          int jj = tid >> 2, k16 = (tid & 3) * 16;
          const float* src = WUd + (unsigned)(jc * 128 + jj) * 768 + 512 + kc * 64 + k16;
#pragma unroll
          for (int s4 = 0; s4 < 4; ++s4) {
            float4 wv = *(const float4*)(src + s4 * 4);
            Wdc[(k16 + s4*4 + 0) * 128 + jj] = wv.x;
            Wdc[(k16 + s4*4 + 1) * 128 + jj] = wv.y;
            Wdc[(k16 + s4*4 + 2) * 128 + jj] = wv.z;
            Wdc[(k16 + s4*4 + 3) * 128 + jj] = wv.w;
          }
        }
        __syncthreads();
#pragma unroll 8
        for (int kk = 0; kk < 64; ++kk) {
          float4 xv = *(const float4*)(XeT + kk * 64 + tt2 * 4);
          float4 wv = *(const float4*)(Wdc + kk * 128 + jq * 4);
          FMA16V(c0, c1, c2, c3, wv, xv);
        }
      }
      int jb = jc * 128 + jq * 4;
      *(float4*)(XeWt + ((unsigned)bid * 256 + jb + 0) * 64 + tt2 * 4) = c0;
      *(float4*)(XeWt + ((unsigned)bid * 256 + jb + 1) * 64 + tt2 * 4) = c1;
      *(float4*)(XeWt + ((unsigned)bid * 256 + jb + 2) * 64 + tt2 * 4) = c2;
      *(float4*)(XeWt + ((unsigned)bid * 256 + jb + 3) * 64 + tt2 * 4) = c3;
    }
    __syncthreads();
  }

  // hoist decoder regs; wreg for ROTATED row jfixD
  float wreg[32];
#pragma unroll
  for (int c = 0; c < 32; ++c) wreg[c] = wudT[c * 256 + jfixD];
  float4 bsD = {0,0,0,0}, wiD = {0,0,0,0};
  {
    int m2 = tid & 15;
    bsD.x = bsum_d[m2]; bsD.y = bsum_d[16 + m2]; bsD.z = bsum_d[32 + m2]; bsD.w = bsum_d[48 + m2];
    wiD.x = wihd_s[m2]; wiD.y = wihd_s[16 + m2]; wiD.z = wihd_s[32 + m2]; wiD.w = wihd_s[48 + m2];
  }
  // xewreg: wave w (0-3), lane l = t': j in w*64..+63
  float xewreg[64];
  if (tid < 256) {
    int w = tid >> 6, l = tid & 63;
    const float* xew = XeWt + (unsigned)bid * 16384 + l;
#pragma unroll
    for (int jj = 0; jj < 64; ++jj) xewreg[jj] = xew[(w * 64 + jj) << 6];
  }
  float cd_reg = 0.f;

  // ================ DECODER: 63 steps ================
  for (int t = 0; t < 63; ++t) {
    const int rd = t & 1, wr2 = (t + 1) & 1;
    const int ml = (tid >> 2) & 15, b4 = tid & 3;
    float* hT  = SCR + 2048;     // [256][20]
    float* red = SCR + 7168;     // [256][20]

    bar_wait(barp, barn);        // Sd(rd), h(rd) visible

    if (tid < 256) {
      // ---- attention (waves 0-3), arrives event B (wave 0)
      int w = tid >> 6, l = tid & 63;
      float* Sdj  = SCR;         // [256]
      float* lp   = SCR + 256;   // [4][64]
      float* beta = SCR + 512;   // [64]
      float* r8   = SCR + 576;   // [8]
      Sdj[w * 64 + l] = ld1s_sc1(ws + OFF_SDB + (unsigned)rd * 65536 + (unsigned)bid * 256 + w * 64 + l);
      lgk0();
      float lpar = 0.f;
#pragma unroll 8
      for (int jj = 0; jj < 64; ++jj)
        lpar += vd_s[w * 64 + jj] * fast_tanh(xewreg[jj] + Sdj[w * 64 + jj]);
      lp[w * 64 + l] = lpar;
      lgk0();
      if (l == 0) lds_inc(FLG + F_L);
      if (w == 0) {
        lds_poll(FLG + F_L, 4u * (t + 1));
        float lv = lp[l] + lp[64 + l] + lp[128 + l] + lp[192 + l];
        float mx = wave_max(lv);
        float ex = __expf(lv - mx);
        float sw = wave_sum(ex);
        beta[l] = ex * __builtin_amdgcn_rcpf(sw);
        lgk0();
        if (l == 0) lds_inc(FLG + F_B);
      }
      lds_poll(FLG + F_B, (unsigned)(t + 1));
      lgk0();
      float ctx = 0.f;
#pragma unroll
      for (int tt = 0; tt < 64; ++tt) ctx += beta[tt] * xe[tt];
      st1_sc1(ws + OFF_CTX + (unsigned)bid * 256 + tid, ctx);
      float yp = ctx * wbt_s[1 + tid];
      float swv = wave_sum(yp);
      if (l == 0) r8[w] = swv;
      lgk0();
      if (l == 0) lds_inc(FLG + F_Y);
      if (w == 0) {
        lds_poll(FLG + F_Y, 4u * (t + 1));
        if (l == 0) {
          float yt = wbt_s[0] * in[bid * 8256 + t * 129 + 128] + r8[0] + r8[1] + r8[2] + r8[3];
          st1_sc1(ws + OFF_YT + bid, yt);
        }
        vm0();
        if (tid == 0)
          __hip_atomic_fetch_add(barp, 1u, __ATOMIC_RELAXED, __HIP_MEMORY_SCOPE_AGENT);
      }
    } else {
      // ---- full K=256 GEMM (waves 4-7) + red write
      int u = tid - 256;
      float4 h0, h1, h2, h3;
      const float* hb = ws + OFF_HD + (unsigned)rd * 65536 + (unsigned)grp * 4096 + u * 16;
      ld1q_nw(h0, hb); ld1q_nw(h1, hb + 4); ld1q_nw(h2, hb + 8); ld1q_nw(h3, hb + 12);
      vm0();
      float* row = hT + (unsigned)u * 20;
      *(float4*)(row + 0) = h0; *(float4*)(row + 4) = h1;
      *(float4*)(row + 8) = h2; *(float4*)(row + 12) = h3;
      lgk0();
      int s = u >> 6;
      float4 a0 = {0,0,0,0}, a1 = {0,0,0,0}, a2 = {0,0,0,0}, a3 = {0,0,0,0};
      const float* xp = hT + (unsigned)(s * 64) * 20 + b4 * 4;
      const float* wp = SLAB + (unsigned)(s * 64) * 64 + ml * 4;
#pragma unroll 8
      for (int kk = 0; kk < 64; ++kk) {
        float4 xv = *(const float4*)(xp + kk * 20);
        float4 wv = *(const float4*)(wp + kk * 64);
        FMA16V(a0, a1, a2, a3, xv, wv);
      }
      float* rp = red + (unsigned)(s * 64 + ml * 4 + b4) * 20;
      *(float4*)(rp + 0) = a0; *(float4*)(rp + 4) = a1;
      *(float4*)(rp + 8) = a2; *(float4*)(rp + 12) = a3;
    }
    barn += 16;
    __syncthreads();             // rejoin (red complete)

    float4 gate = {0,0,0,0};
    if (tid < 256) {
      int m2 = tid & 15, bl = tid >> 4;
      int t2 = m2 * 4 + (bl >> 2), bs = bl & 3;
#pragma unroll
      for (int k2 = 0; k2 < 4; ++k2) {
        float4 rr = *(const float4*)(red + (unsigned)(k2 * 64 + t2) * 20 + bs * 4);
        gate.x += rr.x; gate.y += rr.y; gate.z += rr.z; gate.w += rr.w;
      }
    }
    bar_wait(barp, barn);        // yt visible
    if (tid < 64) {              // zero Sd[rd][bid]
      float* sp = ws + OFF_SDB + (unsigned)rd * 65536 + (unsigned)bid * 256 + tid * 4;
      st1_sc1(sp + 0, 0.f); st1_sc1(sp + 1, 0.f);
      st1_sc1(sp + 2, 0.f); st1_sc1(sp + 3, 0.f);
    }
    float* hcs = SCR;            // [16][32] (attention scratch dead)
    if (tid < 256) {
      int m2 = tid & 15, bl = tid >> 4;
      float yt_reg = ld1s_sc1(ws + OFF_YT + b0 + bl);
      float gi = gate.x + yt_reg * wiD.x + bsD.x;
      float gf = gate.y + yt_reg * wiD.y + bsD.y;
      float gg = gate.z + yt_reg * wiD.z + bsD.z;
      float go = gate.w + yt_reg * wiD.w + bsD.w;
      float cn = fast_sig(gf) * cd_reg + fast_sig(gi) * fast_tanh(gg);
      float hn = fast_sig(go) * fast_tanh(cn);
      cd_reg = cn;
      unsigned m = mt * 16 + m2;
      st1_sc1(ws + OFF_HD + (unsigned)wr2 * 65536 + (unsigned)grp * 4096 + m * 16 + bl, hn);
      hcs[bl * 32 + m2] = hn;
      hcs[bl * 32 + 16 + m2] = cn;
    }
    __syncthreads();
    {  // Sd atomics: 8 batches per thread, ROTATED row jfixD (de-conflicted)
      int half = tid >> 8;
#pragma unroll
      for (int e2 = 0; e2 < 8; ++e2) {
        int bl2 = half * 8 + e2;
        const float* hp = hcs + bl2 * 32;
        float s = 0.f;
#pragma unroll
        for (int c = 0; c < 16; ++c) s += hp[c] * wreg[c];
#pragma unroll
        for (int c = 0; c < 16; ++c) s += hp[16 + c] * wreg[16 + c];
        atomic_add_sc1(ws + OFF_SDB + (unsigned)wr2 * 65536 + (unsigned)(b0 + bl2) * 256 + jfixD, s);
      }
    }
    barn += 16;
    bar_arrive(barp);
  }
  bar_wait(barp, barn);          // h_d, ctx published

  // ---------------- FINAL
  {
    float* hsf  = SCR;          // [16][516]
    float* hid2 = SCR + 8256;   // [2][16][17]
    {
      int l0 = tid * 2, l1 = tid * 2 + 1;
      int k0 = l0 >> 2, i0 = l0 & 3, k1 = l1 >> 2, i1 = l1 & 3;
      const float* hb = ws + OFF_HD + 65536u + (unsigned)grp * 4096;
      int bl0 = l0 >> 6, c0 = (l0 & 63) * 4, bl1 = l1 >> 6, c1 = (l1 & 63) * 4;
      float4 qa, qb, qc, qd;
      ld1q_nw(qa, hb + k0 * 16 + i0 * 4);
      ld1q_nw(qb, hb + k1 * 16 + i1 * 4);
      ld1q_nw(qc, ws + OFF_CTX + (unsigned)(b0 + bl0) * 256 + c0);
      ld1q_nw(qd, ws + OFF_CTX + (unsigned)(b0 + bl1) * 256 + c1);
      vm0();
      hsf[(i0 * 4 + 0) * 516 + k0] = qa.x; hsf[(i0 * 4 + 1) * 516 + k0] = qa.y;
      hsf[(i0 * 4 + 2) * 516 + k0] = qa.z; hsf[(i0 * 4 + 3) * 516 + k0] = qa.w;
      hsf[(i1 * 4 + 0) * 516 + k1] = qb.x; hsf[(i1 * 4 + 1) * 516 + k1] = qb.y;
      hsf[(i1 * 4 + 2) * 516 + k1] = qb.z; hsf[(i1 * 4 + 3) * 516 + k1] = qb.w;
      *(float4*)(hsf + bl0 * 516 + 256 + c0) = qc;
      *(float4*)(hsf + bl1 * 516 + 256 + c1) = qd;
    }
    __syncthreads();
    int bl = tid & 15, p4 = (tid >> 4) & 15, half = tid >> 8;
    int row = mt * 16 + p4;
    const float* wrow = WbW + (unsigned)row * 512 + half * 256;
    const float* hp = hsf + bl * 516 + half * 256;
    float acc = half ? 0.f : Wbb[row];
#pragma unroll 8
    for (int q = 0; q < 64; ++q)
      acc += dot4(*(const float4*)(hp + q * 4), *(const float4*)(wrow + q * 4));
    hid2[half * 272 + bl * 17 + p4] = acc;
    __syncthreads();
    if (tid < 16) {
      float s = 0.f;
#pragma unroll
      for (int p = 0; p < 16; ++p)
        s += (hid2[tid * 17 + p] + hid2[272 + tid * 17 + p]) * vbW[mt * 16 + p];
      if (mt == 0) s += vbb[0];
      atomicAdd(&out[b0 + tid], s);
    }
  }
}

extern "C" void kernel_launch(void* const* d_in, const int* in_sizes, int n_in,
                              void* d_out, int out_size, void* d_ws, size_t ws_size,
                              hipStream_t stream) {
  (void)in_sizes; (void)n_in; (void)out_size; (void)ws_size;
  const float* in    = (const float*)d_in[0];
  const float* WUe   = (const float*)d_in[1];
  const float* ve    = (const float*)d_in[2];
  const float* Wih_e = (const float*)d_in[3];
  const float* Whh_e = (const float*)d_in[4];
  const float* bih_e = (const float*)d_in[5];
  const float* bhh_e = (const float*)d_in[6];
  const float* WUd   = (const float*)d_in[7];
  const float* vd    = (const float*)d_in[8];
  const float* wbt   = (const float*)d_in[9];
  const float* Wih_d = (const float*)d_in[10];
  const float* Whh_d = (const float*)d_in[11];
  const float* bih_d = (const float*)d_in[12];
  const float* bhh_d = (const float*)d_in[13];
  const float* WbW   = (const float*)d_in[14];
  const float* Wbb   = (const float*)d_in[15];
  const float* vbW   = (const float*)d_in[16];
  const float* vbb   = (const float*)d_in[17];
  float* ws  = (float*)d_ws;
  float* out = (float*)d_out;

  (void)hipFuncSetAttribute((const void*)darnn_main,
                            hipFuncAttributeMaxDynamicSharedMemorySize, SMEM_BYTES);
  hipLaunchKernelGGL(darnn_init, dim3(1024), dim3(256), 0, stream, ws, out);
  hipLaunchKernelGGL(darnn_main, dim3(256), dim3(512), SMEM_BYTES, stream,
                     in, WUe, ve, Wih_e, Whh_e, bih_e, bhh_e,
                     WUd, vd, wbt, Wih_d, Whh_d, bih_d, bhh_d,
                     WbW, Wbb, vbW, vbb, ws, out);
}